// Round 1
// baseline (1107.829 us; speedup 1.0000x reference)
//
#include <hip/hip_runtime.h>
#include <cstddef>

// ---------------------------------------------------------------------------
// Problem constants (match reference)
// ---------------------------------------------------------------------------
#define L_SEQ   4096
#define D_MODEL 512
#define D_INNER 1024
#define D_STATE 16
#define DT_RANK 32
#define ATT_D   128
#define NCHUNK  64     // 64 chunks x 64 steps = 4096
#define CLEN    64

// ---------------------------------------------------------------------------
// Generic fp32 SGEMM:  C[M,N] = A[M,K] * B[N,K]^T   (B row-major weights)
// 256 threads, tile BM x BN, per-thread TM x TN, BK = 16.
// Requires M%BM==0, N%BN==0, K%16==0, rows 16B-aligned (all true here).
// ---------------------------------------------------------------------------
template <int BM, int BN, int TM, int TN>
__global__ void __launch_bounds__(256) sgemm(const float* __restrict__ A, int lda,
                                             const float* __restrict__ B, int ldb,
                                             float* __restrict__ C, int ldc,
                                             int M, int N, int K) {
    constexpr int BK = 16;
    __shared__ float As[BK][BM + 4];
    __shared__ float Bs[BK][BN + 4];
    const int tid = threadIdx.x;
    const int tx = tid & 15;        // 0..15 -> n
    const int ty = tid >> 4;        // 0..15 -> m
    const int row0 = blockIdx.y * BM;
    const int col0 = blockIdx.x * BN;

    float acc[TM][TN] = {};

    for (int k0 = 0; k0 < K; k0 += BK) {
        // Stage A tile (BM x BK) as As[k][m]
#pragma unroll
        for (int i = 0; i < (BM * BK) / (256 * 4); ++i) {
            int lin = tid + i * 256;
            int m = lin >> 2;
            int kk = (lin & 3) << 2;
            float4 v = *(const float4*)(A + (size_t)(row0 + m) * lda + k0 + kk);
            As[kk + 0][m] = v.x; As[kk + 1][m] = v.y;
            As[kk + 2][m] = v.z; As[kk + 3][m] = v.w;
        }
        // Stage B tile (BN x BK) as Bs[k][n]
#pragma unroll
        for (int i = 0; i < (BN * BK) / (256 * 4); ++i) {
            int lin = tid + i * 256;
            int m = lin >> 2;
            int kk = (lin & 3) << 2;
            float4 v = *(const float4*)(B + (size_t)(col0 + m) * ldb + k0 + kk);
            Bs[kk + 0][m] = v.x; Bs[kk + 1][m] = v.y;
            Bs[kk + 2][m] = v.z; Bs[kk + 3][m] = v.w;
        }
        __syncthreads();
#pragma unroll
        for (int k = 0; k < BK; ++k) {
            float a[TM], b[TN];
#pragma unroll
            for (int i = 0; i < TM; ++i) a[i] = As[k][ty * TM + i];
#pragma unroll
            for (int j = 0; j < TN; ++j) b[j] = Bs[k][tx * TN + j];
#pragma unroll
            for (int i = 0; i < TM; ++i)
#pragma unroll
                for (int j = 0; j < TN; ++j)
                    acc[i][j] = fmaf(a[i], b[j], acc[i][j]);
        }
        __syncthreads();
    }
#pragma unroll
    for (int i = 0; i < TM; ++i) {
        size_t r = (size_t)(row0 + ty * TM + i);
#pragma unroll
        for (int j = 0; j < TN; ++j)
            C[r * ldc + col0 + tx * TN + j] = acc[i][j];
    }
}

// ---------------------------------------------------------------------------
// Depthwise causal conv (k=4) + bias + silu.  xin = first half of xz rows.
// ---------------------------------------------------------------------------
__global__ void conv_silu_k(const float* __restrict__ XZ, const float* __restrict__ cw,
                            const float* __restrict__ cb, float* __restrict__ U) {
    int i = blockIdx.x * 256 + threadIdx.x;
    if (i >= L_SEQ * D_INNER) return;
    int t = i >> 10;
    int d = i & (D_INNER - 1);
    float acc = cb[d];
#pragma unroll
    for (int k = 0; k < 4; ++k) {
        int tt = t - 3 + k;
        if (tt >= 0) acc = fmaf(cw[d * 4 + k], XZ[(size_t)tt * (2 * D_INNER) + d], acc);
    }
    U[i] = acc / (1.f + __expf(-acc));   // silu
}

// ---------------------------------------------------------------------------
// In-place softplus(x + dt_b[d]) on the dt GEMM output.
// ---------------------------------------------------------------------------
__global__ void softplus_k(float* __restrict__ DT, const float* __restrict__ dtb) {
    int i = blockIdx.x * 256 + threadIdx.x;
    if (i >= L_SEQ * D_INNER) return;
    int d = i & (D_INNER - 1);
    float v = DT[i] + dtb[d];
    DT[i] = (v > 20.f) ? v : log1pf(__expf(v));
}

// ---------------------------------------------------------------------------
// Chunked selective scan.
// Pass 1: per (chunk, d, s): local h (from 0) and chunk decay product P.
// Pass 2: sequential combine over chunks -> incoming state HIN per chunk.
// Pass 3: replay with correct h_in, produce y, fuse +u*D and *silu(z) gate.
// Wave layout: 64 lanes = 4 channels x 16 states.
// ---------------------------------------------------------------------------
__global__ void scan_pass1(const float* __restrict__ DT, const float* __restrict__ U,
                           const float* __restrict__ XDBL, const float* __restrict__ A_log,
                           float* __restrict__ P, float* __restrict__ HLOC) {
    int lane = threadIdx.x;
    int s = lane & 15, dsub = lane >> 4;
    int d = blockIdx.x * 4 + dsub;
    int c = blockIdx.y;
    float Ac = -__expf(A_log[d * D_STATE + s]);
    float h = 0.f, Pp = 1.f;
    int t0 = c * CLEN;
    for (int i = 0; i < CLEN; ++i) {
        int t = t0 + i;
        float dtv = DT[t * D_INNER + d];
        float uu  = U[t * D_INNER + d];
        float Bv  = XDBL[t * 64 + DT_RANK + s];
        float dA  = __expf(dtv * Ac);
        h = fmaf(dA, h, dtv * Bv * uu);
        Pp *= dA;
    }
    int idx = c * (D_INNER * D_STATE) + d * D_STATE + s;
    P[idx] = Pp;
    HLOC[idx] = h;
}

__global__ void scan_pass2(const float* __restrict__ P, const float* __restrict__ HLOC,
                           float* __restrict__ HIN) {
    int g = blockIdx.x * 256 + threadIdx.x;   // 0 .. 16383
    const int STRIDE = D_INNER * D_STATE;
    float h = 0.f;
    for (int c = 0; c < NCHUNK; ++c) {
        HIN[c * STRIDE + g] = h;
        h = fmaf(P[c * STRIDE + g], h, HLOC[c * STRIDE + g]);
    }
}

__global__ void scan_pass3(const float* __restrict__ DT, const float* __restrict__ U,
                           const float* __restrict__ XDBL, const float* __restrict__ A_log,
                           const float* __restrict__ Dp, const float* __restrict__ XZ,
                           const float* __restrict__ HIN, float* __restrict__ G) {
    int lane = threadIdx.x;
    int s = lane & 15, dsub = lane >> 4;
    int d = blockIdx.x * 4 + dsub;
    int c = blockIdx.y;
    float Ac = -__expf(A_log[d * D_STATE + s]);
    float Dv = Dp[d];
    float h = HIN[c * (D_INNER * D_STATE) + d * D_STATE + s];
    int t0 = c * CLEN;
    for (int i = 0; i < CLEN; ++i) {
        int t = t0 + i;
        float dtv = DT[t * D_INNER + d];
        float uu  = U[t * D_INNER + d];
        float Bv  = XDBL[t * 64 + DT_RANK + s];
        float Cv  = XDBL[t * 64 + DT_RANK + D_STATE + s];
        float dA  = __expf(dtv * Ac);
        h = fmaf(dA, h, dtv * Bv * uu);
        float p = h * Cv;
        p += __shfl_xor(p, 8);
        p += __shfl_xor(p, 4);
        p += __shfl_xor(p, 2);
        p += __shfl_xor(p, 1);
        if (s == 0) {
            float y = p + uu * Dv;
            float z = XZ[(size_t)t * (2 * D_INNER) + D_INNER + d];
            float sz = z / (1.f + __expf(-z));
            G[t * D_INNER + d] = y * sz;
        }
    }
}

// ---------------------------------------------------------------------------
// Attention head:  logits[t] = tanh(x[t]@w1^T + b1) @ w2^T + b2
// (HA = x@w1^T precomputed by sgemm).
// ---------------------------------------------------------------------------
__global__ void attn_logits(const float* __restrict__ ha, const float* __restrict__ b1,
                            const float* __restrict__ w2, const float* __restrict__ b2,
                            float* __restrict__ logit) {
    int t = blockIdx.x * 256 + threadIdx.x;
    if (t >= L_SEQ) return;
    float acc = b2[0];
#pragma unroll 4
    for (int j = 0; j < ATT_D; ++j)
        acc = fmaf(tanhf(ha[(size_t)t * ATT_D + j] + b1[j]), w2[j], acc);
    logit[t] = acc;
}

__global__ void softmax_weights(const float* __restrict__ logit, float* __restrict__ w) {
    __shared__ float red[256];
    int tid = threadIdx.x;
    float m = -1e30f;
    for (int t = tid; t < L_SEQ; t += 256) m = fmaxf(m, logit[t]);
    red[tid] = m;
    __syncthreads();
    for (int s = 128; s > 0; s >>= 1) {
        if (tid < s) red[tid] = fmaxf(red[tid], red[tid + s]);
        __syncthreads();
    }
    m = red[0];
    __syncthreads();
    float sum = 0.f;
    for (int t = tid; t < L_SEQ; t += 256) sum += __expf(logit[t] - m);
    red[tid] = sum;
    __syncthreads();
    for (int s = 128; s > 0; s >>= 1) {
        if (tid < s) red[tid] += red[tid + s];
        __syncthreads();
    }
    float inv = 1.f / red[0];
    for (int t = tid; t < L_SEQ; t += 256) w[t] = __expf(logit[t] - m) * inv;
}

// out[j] = sum_t w[t] * F2[t, j];  grid (8 j-groups of 64, 8 t-chunks of 512)
__global__ void weighted_sum(const float* __restrict__ w, const float* __restrict__ f,
                             float* __restrict__ out) {
    int jl = threadIdx.x & 63, tq = threadIdx.x >> 6;
    int j = blockIdx.x * 64 + jl;
    float acc = 0.f;
    int tbase = blockIdx.y * 512 + tq * 128;
    for (int i = 0; i < 128; ++i) {
        int t = tbase + i;
        acc = fmaf(w[t], f[(size_t)t * D_MODEL + j], acc);
    }
    __shared__ float sred[4][64];
    sred[tq][jl] = acc;
    __syncthreads();
    if (tq == 0)
        atomicAdd(&out[j], sred[0][jl] + sred[1][jl] + sred[2][jl] + sred[3][jl]);
}

// ---------------------------------------------------------------------------
// Host-side orchestration
// ---------------------------------------------------------------------------
extern "C" void kernel_launch(void* const* d_in, const int* in_sizes, int n_in,
                              void* d_out, int out_size, void* d_ws, size_t ws_size,
                              hipStream_t stream) {
    (void)in_sizes; (void)n_in; (void)out_size; (void)ws_size;
    const float* x = (const float*)d_in[0];
    const float* m_in_w[2]   = {(const float*)d_in[1],  (const float*)d_in[10]};
    const float* m_conv_w[2] = {(const float*)d_in[2],  (const float*)d_in[11]};
    const float* m_conv_b[2] = {(const float*)d_in[3],  (const float*)d_in[12]};
    const float* m_xproj[2]  = {(const float*)d_in[4],  (const float*)d_in[13]};
    const float* m_dt_w[2]   = {(const float*)d_in[5],  (const float*)d_in[14]};
    const float* m_dt_b[2]   = {(const float*)d_in[6],  (const float*)d_in[15]};
    const float* m_A_log[2]  = {(const float*)d_in[7],  (const float*)d_in[16]};
    const float* m_D[2]      = {(const float*)d_in[8],  (const float*)d_in[17]};
    const float* m_out_w[2]  = {(const float*)d_in[9],  (const float*)d_in[18]};
    const float* attn_w1 = (const float*)d_in[19];
    const float* attn_b1 = (const float*)d_in[20];
    const float* attn_w2 = (const float*)d_in[21];
    const float* attn_b2 = (const float*)d_in[22];

    const int L = L_SEQ;
    float* ws   = (float*)d_ws;
    float* XZ   = ws;                                  // L*2048
    float* U    = XZ   + (size_t)L * 2048;             // L*1024
    float* XDBL = U    + (size_t)L * 1024;             // L*64
    float* DT   = XDBL + (size_t)L * 64;               // L*1024
    float* G    = DT   + (size_t)L * 1024;             // L*1024
    float* F1   = G    + (size_t)L * 1024;             // L*512
    float* P    = F1   + (size_t)L * 512;              // 64*16384
    float* HLOC = P    + (size_t)NCHUNK * D_INNER * D_STATE;
    float* HIN  = HLOC + (size_t)NCHUNK * D_INNER * D_STATE;
    float* HA   = HIN  + (size_t)NCHUNK * D_INNER * D_STATE;  // L*128
    float* LOGIT= HA   + (size_t)L * ATT_D;            // L
    float* WSM  = LOGIT + L;                           // L
    float* F2   = U;   // reuse: U is dead after mamba2's scan pass3

    auto mamba = [&](const float* inp, int b, float* Fout) {
        // xz = inp @ in_w^T   (4096 x 2048, K=512)
        sgemm<128, 64, 8, 4><<<dim3(2048 / 64, L / 128), 256, 0, stream>>>(
            inp, D_MODEL, m_in_w[b], D_MODEL, XZ, 2 * D_INNER, L, 2 * D_INNER, D_MODEL);
        // u = silu(causal_conv(xin) + cb)
        conv_silu_k<<<(L * D_INNER + 255) / 256, 256, 0, stream>>>(XZ, m_conv_w[b], m_conv_b[b], U);
        // xdbl = u @ xproj^T  (4096 x 64, K=1024)
        sgemm<64, 64, 4, 4><<<dim3(1, L / 64), 256, 0, stream>>>(
            U, D_INNER, m_xproj[b], D_INNER, XDBL, 64, L, 64, D_INNER);
        // dt_raw = xdbl[:, :32] @ dt_w^T  (4096 x 1024, K=32)
        sgemm<64, 64, 4, 4><<<dim3(D_INNER / 64, L / 64), 256, 0, stream>>>(
            XDBL, 64, m_dt_w[b], DT_RANK, DT, D_INNER, L, D_INNER, DT_RANK);
        // dt = softplus(dt_raw + dt_b)
        softplus_k<<<(L * D_INNER + 255) / 256, 256, 0, stream>>>(DT, m_dt_b[b]);
        // chunked scan -> gated output G
        scan_pass1<<<dim3(D_INNER / 4, NCHUNK), 64, 0, stream>>>(DT, U, XDBL, m_A_log[b], P, HLOC);
        scan_pass2<<<(D_INNER * D_STATE) / 256, 256, 0, stream>>>(P, HLOC, HIN);
        scan_pass3<<<dim3(D_INNER / 4, NCHUNK), 64, 0, stream>>>(DT, U, XDBL, m_A_log[b],
                                                                 m_D[b], XZ, HIN, G);
        // f = G @ out_w^T  (4096 x 512, K=1024)
        sgemm<128, 64, 8, 4><<<dim3(D_MODEL / 64, L / 128), 256, 0, stream>>>(
            G, D_INNER, m_out_w[b], D_INNER, Fout, D_MODEL, L, D_MODEL, D_INNER);
    };

    mamba(x, 0, F1);
    mamba(F1, 1, F2);

    // attention: HA = x @ w1^T  (4096 x 128, K=512)
    sgemm<64, 64, 4, 4><<<dim3(ATT_D / 64, L / 64), 256, 0, stream>>>(
        x, D_MODEL, attn_w1, D_MODEL, HA, ATT_D, L, ATT_D, D_MODEL);
    attn_logits<<<(L + 255) / 256, 256, 0, stream>>>(HA, attn_b1, attn_w2, attn_b2, LOGIT);
    softmax_weights<<<1, 256, 0, stream>>>(LOGIT, WSM);
    hipMemsetAsync(d_out, 0, D_MODEL * sizeof(float), stream);
    weighted_sum<<<dim3(D_MODEL / 64, 8), 256, 0, stream>>>(WSM, F2, (float*)d_out);
}

// Round 2
// 860.291 us; speedup vs baseline: 1.2877x; 1.2877x over previous
//
#include <hip/hip_runtime.h>
#include <cstddef>
#include <cstdint>

// ---------------------------------------------------------------------------
// Problem constants (match reference)
// ---------------------------------------------------------------------------
#define L_SEQ   4096
#define D_MODEL 512
#define D_INNER 1024
#define D_STATE 16
#define DT_RANK 32
#define ATT_D   128
#define NCHUNK  64     // 64 chunks x 64 steps = 4096
#define CLEN    64

typedef __bf16 bf16;
typedef __bf16 bf16x8 __attribute__((ext_vector_type(8)));
typedef float  f32x4  __attribute__((ext_vector_type(4)));

__device__ __forceinline__ void load_lds16(const void* g, void* l) {
    __builtin_amdgcn_global_load_lds(
        (const __attribute__((address_space(1))) uint32_t*)g,
        (__attribute__((address_space(3))) uint32_t*)l, 16, 0, 0);
}

// ---------------------------------------------------------------------------
// bf16 MFMA GEMM:  C[M,N] = A[M,K] * B[N,K]^T, fp32 accumulate/output.
// A,B are pre-split "augmented" bf16 (K' = 3*K_orig).  m97-style structure:
// global_load_lds width-16 staging, 2-barrier K-loop, 16x16x32 MFMA.
// Block = 256 threads = 4 waves in 2x2; wave tile = (BM/2)x(BN/2).
// ---------------------------------------------------------------------------
template <int BM, int BN>
__global__ void __launch_bounds__(256) gemm_bf16(const bf16* __restrict__ A,
                                                 const bf16* __restrict__ B,
                                                 float* __restrict__ C,
                                                 int M, int N, int K) {
    constexpr int BK = 32;
    constexpr int TM = BM / 32;   // 16x16 tiles per wave, m dir
    constexpr int TN = BN / 32;   // n dir
    __shared__ bf16 As[BM][BK];
    __shared__ bf16 Bs[BN][BK];
    const int tid  = threadIdx.x;
    const int lane = tid & 63;
    const int wid  = tid >> 6;
    const int wm   = wid >> 1;
    const int wn   = wid & 1;
    const int m_l  = lane & 15;
    const int quad = lane >> 4;
    const int row0 = blockIdx.y * BM;
    const int col0 = blockIdx.x * BN;

    f32x4 acc[TM][TN] = {};

    const int ar = tid >> 2;        // staging row within tile (round 0)
    const int ac = (tid & 3) * 8;   // staging col (elements), 16B chunk

    for (int k0 = 0; k0 < K; k0 += BK) {
#pragma unroll
        for (int r = 0; r < BM / 64; ++r)
            load_lds16(A + (size_t)(row0 + ar + r * 64) * K + k0 + ac,
                       (char*)&As[0][0] + (tid + r * 256) * 16);
#pragma unroll
        for (int r = 0; r < BN / 64; ++r)
            load_lds16(B + (size_t)(col0 + ar + r * 64) * K + k0 + ac,
                       (char*)&Bs[0][0] + (tid + r * 256) * 16);
        __syncthreads();   // drains vmcnt (global_load_lds) + lgkm

        bf16x8 af[TM], bfr[TN];
#pragma unroll
        for (int i = 0; i < TM; ++i)
            af[i] = *(const bf16x8*)&As[wm * (BM / 2) + i * 16 + m_l][quad * 8];
#pragma unroll
        for (int j = 0; j < TN; ++j)
            bfr[j] = *(const bf16x8*)&Bs[wn * (BN / 2) + j * 16 + m_l][quad * 8];
#pragma unroll
        for (int i = 0; i < TM; ++i)
#pragma unroll
            for (int j = 0; j < TN; ++j)
                acc[i][j] = __builtin_amdgcn_mfma_f32_16x16x32_bf16(
                                af[i], bfr[j], acc[i][j], 0, 0, 0);
        __syncthreads();
    }
    // C/D layout (m89-verified): col = lane&15, row = quad*4 + reg
#pragma unroll
    for (int i = 0; i < TM; ++i)
#pragma unroll
        for (int j = 0; j < TN; ++j) {
            int rr = row0 + wm * (BM / 2) + i * 16 + quad * 4;
            int cc = col0 + wn * (BN / 2) + j * 16 + m_l;
#pragma unroll
            for (int g = 0; g < 4; ++g)
                C[(size_t)(rr + g) * N + cc] = acc[i][j][g];
        }
}

// ---------------------------------------------------------------------------
// fp32 -> augmented bf16 splits.
// act: rows [hi | lo | hi]   wt: rows [hi | hi | lo]
// so that  act' . wt' = hi*hi + lo*hi + hi*lo  (error ~2^-17 relative)
// ---------------------------------------------------------------------------
__global__ void split3_act_k(const float* __restrict__ X, bf16* __restrict__ Y,
                             int K, int total) {
    int i = blockIdx.x * 256 + threadIdx.x;
    if (i >= total) return;
    int row = i / K, col = i - row * K;
    float v = X[i];
    bf16 h = (bf16)v;
    bf16 l = (bf16)(v - (float)h);
    bf16* yr = Y + (size_t)row * 3 * K;
    yr[col] = h; yr[K + col] = l; yr[2 * K + col] = h;
}

__global__ void split3_wt_k(const float* __restrict__ X, bf16* __restrict__ Y,
                            int K, int total) {
    int i = blockIdx.x * 256 + threadIdx.x;
    if (i >= total) return;
    int row = i / K, col = i - row * K;
    float v = X[i];
    bf16 h = (bf16)v;
    bf16 l = (bf16)(v - (float)h);
    bf16* yr = Y + (size_t)row * 3 * K;
    yr[col] = h; yr[K + col] = h; yr[2 * K + col] = l;
}

// ---------------------------------------------------------------------------
// fp32 SGEMM (kept for small GEMMs):  C = A[M,K] * B[N,K]^T.
// Optional split-K via gridDim.z: slice z handles K/nz, writes C + z*M*ldc.
// ---------------------------------------------------------------------------
template <int BM, int BN, int TM, int TN>
__global__ void __launch_bounds__(256) sgemm(const float* __restrict__ A, int lda,
                                             const float* __restrict__ B, int ldb,
                                             float* __restrict__ C, int ldc,
                                             int M, int N, int K) {
    constexpr int BK = 16;
    __shared__ float As[BK][BM + 4];
    __shared__ float Bs[BK][BN + 4];
    const int tid = threadIdx.x;
    const int tx = tid & 15;
    const int ty = tid >> 4;
    const int row0 = blockIdx.y * BM;
    const int col0 = blockIdx.x * BN;
    const int nz = gridDim.z;
    const int kper = K / nz;
    const int kbeg = blockIdx.z * kper, kend = kbeg + kper;
    float* Cz = C + (size_t)blockIdx.z * M * ldc;

    float acc[TM][TN] = {};

    for (int k0 = kbeg; k0 < kend; k0 += BK) {
#pragma unroll
        for (int i = 0; i < (BM * BK) / (256 * 4); ++i) {
            int lin = tid + i * 256;
            int m = lin >> 2;
            int kk = (lin & 3) << 2;
            float4 v = *(const float4*)(A + (size_t)(row0 + m) * lda + k0 + kk);
            As[kk + 0][m] = v.x; As[kk + 1][m] = v.y;
            As[kk + 2][m] = v.z; As[kk + 3][m] = v.w;
        }
#pragma unroll
        for (int i = 0; i < (BN * BK) / (256 * 4); ++i) {
            int lin = tid + i * 256;
            int m = lin >> 2;
            int kk = (lin & 3) << 2;
            float4 v = *(const float4*)(B + (size_t)(col0 + m) * ldb + k0 + kk);
            Bs[kk + 0][m] = v.x; Bs[kk + 1][m] = v.y;
            Bs[kk + 2][m] = v.z; Bs[kk + 3][m] = v.w;
        }
        __syncthreads();
#pragma unroll
        for (int k = 0; k < BK; ++k) {
            float a[TM], b[TN];
#pragma unroll
            for (int i = 0; i < TM; ++i) a[i] = As[k][ty * TM + i];
#pragma unroll
            for (int j = 0; j < TN; ++j) b[j] = Bs[k][tx * TN + j];
#pragma unroll
            for (int i = 0; i < TM; ++i)
#pragma unroll
                for (int j = 0; j < TN; ++j)
                    acc[i][j] = fmaf(a[i], b[j], acc[i][j]);
        }
        __syncthreads();
    }
#pragma unroll
    for (int i = 0; i < TM; ++i) {
        size_t r = (size_t)(row0 + ty * TM + i);
#pragma unroll
        for (int j = 0; j < TN; ++j)
            Cz[r * ldc + col0 + tx * TN + j] = acc[i][j];
    }
}

__global__ void reduce4_k(const float* __restrict__ Pp, float* __restrict__ Y, int n) {
    int i = blockIdx.x * 256 + threadIdx.x;
    if (i >= n) return;
    Y[i] = (Pp[i] + Pp[i + n]) + (Pp[i + 2 * n] + Pp[i + 3 * n]);
}

// ---------------------------------------------------------------------------
// Depthwise causal conv (k=4) + bias + silu
// ---------------------------------------------------------------------------
__global__ void conv_silu_k(const float* __restrict__ XZ, const float* __restrict__ cw,
                            const float* __restrict__ cb, float* __restrict__ U) {
    int i = blockIdx.x * 256 + threadIdx.x;
    if (i >= L_SEQ * D_INNER) return;
    int t = i >> 10;
    int d = i & (D_INNER - 1);
    float acc = cb[d];
#pragma unroll
    for (int k = 0; k < 4; ++k) {
        int tt = t - 3 + k;
        if (tt >= 0) acc = fmaf(cw[d * 4 + k], XZ[(size_t)tt * (2 * D_INNER) + d], acc);
    }
    U[i] = acc / (1.f + __expf(-acc));
}

__global__ void softplus_k(float* __restrict__ DT, const float* __restrict__ dtb) {
    int i = blockIdx.x * 256 + threadIdx.x;
    if (i >= L_SEQ * D_INNER) return;
    int d = i & (D_INNER - 1);
    float v = DT[i] + dtb[d];
    DT[i] = (v > 20.f) ? v : log1pf(__expf(v));
}

// ---------------------------------------------------------------------------
// Chunked selective scan (3-pass, exact)
// ---------------------------------------------------------------------------
__global__ void scan_pass1(const float* __restrict__ DT, const float* __restrict__ U,
                           const float* __restrict__ XDBL, const float* __restrict__ A_log,
                           float* __restrict__ P, float* __restrict__ HLOC) {
    int lane = threadIdx.x;
    int s = lane & 15, dsub = lane >> 4;
    int d = blockIdx.x * 4 + dsub;
    int c = blockIdx.y;
    float Ac = -__expf(A_log[d * D_STATE + s]);
    float h = 0.f, Pp = 1.f;
    int t0 = c * CLEN;
    for (int i = 0; i < CLEN; ++i) {
        int t = t0 + i;
        float dtv = DT[t * D_INNER + d];
        float uu  = U[t * D_INNER + d];
        float Bv  = XDBL[t * 64 + DT_RANK + s];
        float dA  = __expf(dtv * Ac);
        h = fmaf(dA, h, dtv * Bv * uu);
        Pp *= dA;
    }
    int idx = c * (D_INNER * D_STATE) + d * D_STATE + s;
    P[idx] = Pp;
    HLOC[idx] = h;
}

__global__ void scan_pass2(const float* __restrict__ P, const float* __restrict__ HLOC,
                           float* __restrict__ HIN) {
    int g = blockIdx.x * 256 + threadIdx.x;
    const int STRIDE = D_INNER * D_STATE;
    float h = 0.f;
    for (int c = 0; c < NCHUNK; ++c) {
        HIN[c * STRIDE + g] = h;
        h = fmaf(P[c * STRIDE + g], h, HLOC[c * STRIDE + g]);
    }
}

__global__ void scan_pass3(const float* __restrict__ DT, const float* __restrict__ U,
                           const float* __restrict__ XDBL, const float* __restrict__ A_log,
                           const float* __restrict__ Dp, const float* __restrict__ XZ,
                           const float* __restrict__ HIN, float* __restrict__ G) {
    int lane = threadIdx.x;
    int s = lane & 15, dsub = lane >> 4;
    int d = blockIdx.x * 4 + dsub;
    int c = blockIdx.y;
    float Ac = -__expf(A_log[d * D_STATE + s]);
    float Dv = Dp[d];
    float h = HIN[c * (D_INNER * D_STATE) + d * D_STATE + s];
    int t0 = c * CLEN;
    for (int i = 0; i < CLEN; ++i) {
        int t = t0 + i;
        float dtv = DT[t * D_INNER + d];
        float uu  = U[t * D_INNER + d];
        float Bv  = XDBL[t * 64 + DT_RANK + s];
        float Cv  = XDBL[t * 64 + DT_RANK + D_STATE + s];
        float dA  = __expf(dtv * Ac);
        h = fmaf(dA, h, dtv * Bv * uu);
        float p = h * Cv;
        p += __shfl_xor(p, 8);
        p += __shfl_xor(p, 4);
        p += __shfl_xor(p, 2);
        p += __shfl_xor(p, 1);
        if (s == 0) {
            float y = p + uu * Dv;
            float z = XZ[(size_t)t * (2 * D_INNER) + D_INNER + d];
            float sz = z / (1.f + __expf(-z));
            G[t * D_INNER + d] = y * sz;
        }
    }
}

// ---------------------------------------------------------------------------
// Attention head
// ---------------------------------------------------------------------------
__global__ void attn_logits(const float* __restrict__ ha, const float* __restrict__ b1,
                            const float* __restrict__ w2, const float* __restrict__ b2,
                            float* __restrict__ logit) {
    int t = blockIdx.x * 256 + threadIdx.x;
    if (t >= L_SEQ) return;
    float acc = b2[0];
#pragma unroll 4
    for (int j = 0; j < ATT_D; ++j)
        acc = fmaf(tanhf(ha[(size_t)t * ATT_D + j] + b1[j]), w2[j], acc);
    logit[t] = acc;
}

__global__ void softmax_weights(const float* __restrict__ logit, float* __restrict__ w) {
    __shared__ float red[256];
    int tid = threadIdx.x;
    float m = -1e30f;
    for (int t = tid; t < L_SEQ; t += 256) m = fmaxf(m, logit[t]);
    red[tid] = m;
    __syncthreads();
    for (int s = 128; s > 0; s >>= 1) {
        if (tid < s) red[tid] = fmaxf(red[tid], red[tid + s]);
        __syncthreads();
    }
    m = red[0];
    __syncthreads();
    float sum = 0.f;
    for (int t = tid; t < L_SEQ; t += 256) sum += __expf(logit[t] - m);
    red[tid] = sum;
    __syncthreads();
    for (int s = 128; s > 0; s >>= 1) {
        if (tid < s) red[tid] += red[tid + s];
        __syncthreads();
    }
    float inv = 1.f / red[0];
    for (int t = tid; t < L_SEQ; t += 256) w[t] = __expf(logit[t] - m) * inv;
}

__global__ void weighted_sum(const float* __restrict__ w, const float* __restrict__ f,
                             float* __restrict__ out) {
    int jl = threadIdx.x & 63, tq = threadIdx.x >> 6;
    int j = blockIdx.x * 64 + jl;
    float acc = 0.f;
    int tbase = blockIdx.y * 512 + tq * 128;
    for (int i = 0; i < 128; ++i) {
        int t = tbase + i;
        acc = fmaf(w[t], f[(size_t)t * D_MODEL + j], acc);
    }
    __shared__ float sred[4][64];
    sred[tq][jl] = acc;
    __syncthreads();
    if (tq == 0)
        atomicAdd(&out[j], sred[0][jl] + sred[1][jl] + sred[2][jl] + sred[3][jl]);
}

// ---------------------------------------------------------------------------
// Host-side orchestration
// ---------------------------------------------------------------------------
extern "C" void kernel_launch(void* const* d_in, const int* in_sizes, int n_in,
                              void* d_out, int out_size, void* d_ws, size_t ws_size,
                              hipStream_t stream) {
    (void)in_sizes; (void)n_in; (void)out_size; (void)ws_size;
    const float* x = (const float*)d_in[0];
    const float* m_in_w[2]   = {(const float*)d_in[1],  (const float*)d_in[10]};
    const float* m_conv_w[2] = {(const float*)d_in[2],  (const float*)d_in[11]};
    const float* m_conv_b[2] = {(const float*)d_in[3],  (const float*)d_in[12]};
    const float* m_xproj[2]  = {(const float*)d_in[4],  (const float*)d_in[13]};
    const float* m_dt_w[2]   = {(const float*)d_in[5],  (const float*)d_in[14]};
    const float* m_dt_b[2]   = {(const float*)d_in[6],  (const float*)d_in[15]};
    const float* m_A_log[2]  = {(const float*)d_in[7],  (const float*)d_in[16]};
    const float* m_D[2]      = {(const float*)d_in[8],  (const float*)d_in[17]};
    const float* m_out_w[2]  = {(const float*)d_in[9],  (const float*)d_in[18]};
    const float* attn_w1 = (const float*)d_in[19];
    const float* attn_b1 = (const float*)d_in[20];
    const float* attn_w2 = (const float*)d_in[21];
    const float* attn_b2 = (const float*)d_in[22];

    const int L = L_SEQ;
    float* ws   = (float*)d_ws;
    float* XZ   = ws;                                  // L*2048
    float* U    = XZ   + (size_t)L * 2048;             // L*1024
    float* XDBL = U    + (size_t)L * 1024;             // L*64
    float* DT   = XDBL + (size_t)L * 64;               // L*1024
    float* G    = DT   + (size_t)L * 1024;             // L*1024
    float* F1   = G    + (size_t)L * 1024;             // L*512
    float* P    = F1   + (size_t)L * 512;              // 64*16384
    float* HLOC = P    + (size_t)NCHUNK * D_INNER * D_STATE;
    float* HIN  = HLOC + (size_t)NCHUNK * D_INNER * D_STATE;
    float* HA   = HIN  + (size_t)NCHUNK * D_INNER * D_STATE;  // L*128
    float* LOGIT= HA   + (size_t)L * ATT_D;            // L
    float* WSM  = LOGIT + L;                           // L
    float* F2   = U;     // U dead after mamba2 scan pass3

    // bf16 augmented buffers overlaid on dead fp32 regions (lifetimes checked):
    bf16* AaugIn  = (bf16*)G;    // 4096x1536 bf16 (3.1M fl)  — G dead until scan3
    bf16* WaugIn  = (bf16*)DT;   // 2048x1536 bf16 (1.6M fl)  — DT dead until dt-gemm
    bf16* AaugOut = (bf16*)XZ;   // 4096x3072 bf16 (6.3M fl)  — XZ dead after scan3
    bf16* WaugOut = (bf16*)DT;   // 512x3072 bf16             — DT dead after scan3
    float* XDBLP  = P;           // 4 x L*64 split-K partials — P dead until scan1

    auto mamba = [&](const float* inp, int b, float* Fout) {
        // ---- in_proj: xz = inp @ in_w^T  via bf16x3 MFMA (K'=1536) ----
        split3_act_k<<<(L * 512 + 255) / 256, 256, 0, stream>>>(inp, AaugIn, D_MODEL, L * 512);
        split3_wt_k<<<(2048 * 512 + 255) / 256, 256, 0, stream>>>(m_in_w[b], WaugIn, D_MODEL, 2048 * 512);
        gemm_bf16<128, 128><<<dim3(2048 / 128, L / 128), 256, 0, stream>>>(
            AaugIn, WaugIn, XZ, L, 2 * D_INNER, 3 * D_MODEL);
        // ---- conv + silu ----
        conv_silu_k<<<(L * D_INNER + 255) / 256, 256, 0, stream>>>(XZ, m_conv_w[b], m_conv_b[b], U);
        // ---- xdbl = u @ xproj^T  (split-K=4 fp32) ----
        sgemm<64, 64, 4, 4><<<dim3(1, L / 64, 4), 256, 0, stream>>>(
            U, D_INNER, m_xproj[b], D_INNER, XDBLP, 64, L, 64, D_INNER);
        reduce4_k<<<(L * 64 + 255) / 256, 256, 0, stream>>>(XDBLP, XDBL, L * 64);
        // ---- dt = softplus(xdbl[:, :32] @ dt_w^T + dt_b) ----
        sgemm<64, 64, 4, 4><<<dim3(D_INNER / 64, L / 64), 256, 0, stream>>>(
            XDBL, 64, m_dt_w[b], DT_RANK, DT, D_INNER, L, D_INNER, DT_RANK);
        softplus_k<<<(L * D_INNER + 255) / 256, 256, 0, stream>>>(DT, m_dt_b[b]);
        // ---- chunked selective scan -> gated G ----
        scan_pass1<<<dim3(D_INNER / 4, NCHUNK), 64, 0, stream>>>(DT, U, XDBL, m_A_log[b], P, HLOC);
        scan_pass2<<<(D_INNER * D_STATE) / 256, 256, 0, stream>>>(P, HLOC, HIN);
        scan_pass3<<<dim3(D_INNER / 4, NCHUNK), 64, 0, stream>>>(DT, U, XDBL, m_A_log[b],
                                                                 m_D[b], XZ, HIN, G);
        // ---- out_proj: f = G @ out_w^T  via bf16x3 MFMA (K'=3072) ----
        split3_act_k<<<(L * 1024 + 255) / 256, 256, 0, stream>>>(G, AaugOut, D_INNER, L * 1024);
        split3_wt_k<<<(512 * 1024 + 255) / 256, 256, 0, stream>>>(m_out_w[b], WaugOut, D_INNER, 512 * 1024);
        gemm_bf16<64, 128><<<dim3(512 / 128, L / 64), 256, 0, stream>>>(
            AaugOut, WaugOut, Fout, L, D_MODEL, 3 * D_INNER);
    };

    mamba(x, 0, F1);
    mamba(F1, 1, F2);

    // attention
    sgemm<64, 64, 4, 4><<<dim3(ATT_D / 64, L / 64), 256, 0, stream>>>(
        x, D_MODEL, attn_w1, D_MODEL, HA, ATT_D, L, ATT_D, D_MODEL);
    attn_logits<<<(L + 255) / 256, 256, 0, stream>>>(HA, attn_b1, attn_w2, attn_b2, LOGIT);
    softmax_weights<<<1, 256, 0, stream>>>(LOGIT, WSM);
    hipMemsetAsync(d_out, 0, D_MODEL * sizeof(float), stream);
    weighted_sum<<<dim3(D_MODEL / 64, 8), 256, 0, stream>>>(WSM, F2, (float*)d_out);
}

// Round 3
// 677.405 us; speedup vs baseline: 1.6354x; 1.2700x over previous
//
#include <hip/hip_runtime.h>
#include <cstddef>
#include <cstdint>

// ---------------------------------------------------------------------------
// Problem constants (match reference)
// ---------------------------------------------------------------------------
#define L_SEQ   4096
#define D_MODEL 512
#define D_INNER 1024
#define D_STATE 16
#define DT_RANK 32
#define ATT_D   128
#define NCHUNK  128    // 128 chunks x 32 steps = 4096
#define CLEN    32

typedef __bf16 bf16;
typedef __bf16 bf16x8 __attribute__((ext_vector_type(8)));
typedef float  f32x4  __attribute__((ext_vector_type(4)));

__device__ __forceinline__ void load_lds16(const void* g, void* l) {
    __builtin_amdgcn_global_load_lds(
        (const __attribute__((address_space(1))) uint32_t*)g,
        (__attribute__((address_space(3))) uint32_t*)l, 16, 0, 0);
}

// ---------------------------------------------------------------------------
// bf16 MFMA GEMM:  C[M,N] = A[M,K] * B[N,K]^T, fp32 accumulate/output.
// A,B are pre-split "augmented" bf16 (K' = 3*K_orig).
// ---------------------------------------------------------------------------
template <int BM, int BN>
__global__ void __launch_bounds__(256) gemm_bf16(const bf16* __restrict__ A,
                                                 const bf16* __restrict__ B,
                                                 float* __restrict__ C,
                                                 int M, int N, int K) {
    constexpr int BK = 32;
    constexpr int TM = BM / 32;
    constexpr int TN = BN / 32;
    __shared__ bf16 As[BM][BK];
    __shared__ bf16 Bs[BN][BK];
    const int tid  = threadIdx.x;
    const int lane = tid & 63;
    const int wid  = tid >> 6;
    const int wm   = wid >> 1;
    const int wn   = wid & 1;
    const int m_l  = lane & 15;
    const int quad = lane >> 4;
    const int row0 = blockIdx.y * BM;
    const int col0 = blockIdx.x * BN;

    f32x4 acc[TM][TN] = {};

    const int ar = tid >> 2;
    const int ac = (tid & 3) * 8;

    for (int k0 = 0; k0 < K; k0 += BK) {
#pragma unroll
        for (int r = 0; r < BM / 64; ++r)
            load_lds16(A + (size_t)(row0 + ar + r * 64) * K + k0 + ac,
                       (char*)&As[0][0] + (tid + r * 256) * 16);
#pragma unroll
        for (int r = 0; r < BN / 64; ++r)
            load_lds16(B + (size_t)(col0 + ar + r * 64) * K + k0 + ac,
                       (char*)&Bs[0][0] + (tid + r * 256) * 16);
        __syncthreads();

        bf16x8 af[TM], bfr[TN];
#pragma unroll
        for (int i = 0; i < TM; ++i)
            af[i] = *(const bf16x8*)&As[wm * (BM / 2) + i * 16 + m_l][quad * 8];
#pragma unroll
        for (int j = 0; j < TN; ++j)
            bfr[j] = *(const bf16x8*)&Bs[wn * (BN / 2) + j * 16 + m_l][quad * 8];
#pragma unroll
        for (int i = 0; i < TM; ++i)
#pragma unroll
            for (int j = 0; j < TN; ++j)
                acc[i][j] = __builtin_amdgcn_mfma_f32_16x16x32_bf16(
                                af[i], bfr[j], acc[i][j], 0, 0, 0);
        __syncthreads();
    }
#pragma unroll
    for (int i = 0; i < TM; ++i)
#pragma unroll
        for (int j = 0; j < TN; ++j) {
            int rr = row0 + wm * (BM / 2) + i * 16 + quad * 4;
            int cc = col0 + wn * (BN / 2) + j * 16 + m_l;
#pragma unroll
            for (int g = 0; g < 4; ++g)
                C[(size_t)(rr + g) * N + cc] = acc[i][j][g];
        }
}

// ---------------------------------------------------------------------------
// fp32 -> augmented bf16 splits.  act: [hi|lo|hi]   wt: [hi|hi|lo]
// ---------------------------------------------------------------------------
__global__ void split3_act_k(const float* __restrict__ X, bf16* __restrict__ Y,
                             int K, int total) {
    int i = blockIdx.x * 256 + threadIdx.x;
    if (i >= total) return;
    int row = i / K, col = i - row * K;
    float v = X[i];
    bf16 h = (bf16)v;
    bf16 l = (bf16)(v - (float)h);
    bf16* yr = Y + (size_t)row * 3 * K;
    yr[col] = h; yr[K + col] = l; yr[2 * K + col] = h;
}

__global__ void split3_wt_k(const float* __restrict__ X, bf16* __restrict__ Y,
                            int K, int total) {
    int i = blockIdx.x * 256 + threadIdx.x;
    if (i >= total) return;
    int row = i / K, col = i - row * K;
    float v = X[i];
    bf16 h = (bf16)v;
    bf16 l = (bf16)(v - (float)h);
    bf16* yr = Y + (size_t)row * 3 * K;
    yr[col] = h; yr[K + col] = h; yr[2 * K + col] = l;
}

// ---------------------------------------------------------------------------
// fp32 SGEMM for the small GEMMs, optional split-K via gridDim.z.
// ---------------------------------------------------------------------------
template <int BM, int BN, int TM, int TN>
__global__ void __launch_bounds__(256) sgemm(const float* __restrict__ A, int lda,
                                             const float* __restrict__ B, int ldb,
                                             float* __restrict__ C, int ldc,
                                             int M, int N, int K) {
    constexpr int BK = 16;
    __shared__ float As[BK][BM + 4];
    __shared__ float Bs[BK][BN + 4];
    const int tid = threadIdx.x;
    const int tx = tid & 15;
    const int ty = tid >> 4;
    const int row0 = blockIdx.y * BM;
    const int col0 = blockIdx.x * BN;
    const int nz = gridDim.z;
    const int kper = K / nz;
    const int kbeg = blockIdx.z * kper, kend = kbeg + kper;
    float* Cz = C + (size_t)blockIdx.z * M * ldc;

    float acc[TM][TN] = {};

    for (int k0 = kbeg; k0 < kend; k0 += BK) {
#pragma unroll
        for (int i = 0; i < (BM * BK) / (256 * 4); ++i) {
            int lin = tid + i * 256;
            int m = lin >> 2;
            int kk = (lin & 3) << 2;
            float4 v = *(const float4*)(A + (size_t)(row0 + m) * lda + k0 + kk);
            As[kk + 0][m] = v.x; As[kk + 1][m] = v.y;
            As[kk + 2][m] = v.z; As[kk + 3][m] = v.w;
        }
#pragma unroll
        for (int i = 0; i < (BN * BK) / (256 * 4); ++i) {
            int lin = tid + i * 256;
            int m = lin >> 2;
            int kk = (lin & 3) << 2;
            float4 v = *(const float4*)(B + (size_t)(col0 + m) * ldb + k0 + kk);
            Bs[kk + 0][m] = v.x; Bs[kk + 1][m] = v.y;
            Bs[kk + 2][m] = v.z; Bs[kk + 3][m] = v.w;
        }
        __syncthreads();
#pragma unroll
        for (int k = 0; k < BK; ++k) {
            float a[TM], b[TN];
#pragma unroll
            for (int i = 0; i < TM; ++i) a[i] = As[k][ty * TM + i];
#pragma unroll
            for (int j = 0; j < TN; ++j) b[j] = Bs[k][tx * TN + j];
#pragma unroll
            for (int i = 0; i < TM; ++i)
#pragma unroll
                for (int j = 0; j < TN; ++j)
                    acc[i][j] = fmaf(a[i], b[j], acc[i][j]);
        }
        __syncthreads();
    }
#pragma unroll
    for (int i = 0; i < TM; ++i) {
        size_t r = (size_t)(row0 + ty * TM + i);
#pragma unroll
        for (int j = 0; j < TN; ++j)
            Cz[r * ldc + col0 + tx * TN + j] = acc[i][j];
    }
}

__global__ void reduce4_k(const float* __restrict__ Pp, float* __restrict__ Y, int n) {
    int i = blockIdx.x * 256 + threadIdx.x;
    if (i >= n) return;
    Y[i] = (Pp[i] + Pp[i + n]) + (Pp[i + 2 * n] + Pp[i + 3 * n]);
}

// ---------------------------------------------------------------------------
// Depthwise causal conv (k=4) + bias + silu
// ---------------------------------------------------------------------------
__global__ void conv_silu_k(const float* __restrict__ XZ, const float* __restrict__ cw,
                            const float* __restrict__ cb, float* __restrict__ U) {
    int i = blockIdx.x * 256 + threadIdx.x;
    if (i >= L_SEQ * D_INNER) return;
    int t = i >> 10;
    int d = i & (D_INNER - 1);
    float acc = cb[d];
#pragma unroll
    for (int k = 0; k < 4; ++k) {
        int tt = t - 3 + k;
        if (tt >= 0) acc = fmaf(cw[d * 4 + k], XZ[(size_t)tt * (2 * D_INNER) + d], acc);
    }
    U[i] = acc / (1.f + __expf(-acc));
}

// ---------------------------------------------------------------------------
// Chunked selective scan, channel-per-lane layout.
// lane = one channel d; 16 states in registers. All DT/U/z/G accesses are
// 256 B/wave coalesced. B/C are wave-uniform (L1 broadcast).
// softplus(dt_raw + dt_b) fused here.
// pass2 converts HLOC -> incoming state (HIN) IN PLACE.
// ---------------------------------------------------------------------------
__device__ __forceinline__ float softplus_f(float v) {
    return (v > 20.f) ? v : log1pf(__expf(v));
}

__global__ void __launch_bounds__(256) scan_pass1(
        const float* __restrict__ DTR, const float* __restrict__ dtb,
        const float* __restrict__ U, const float* __restrict__ XDBL,
        const float* __restrict__ A_log, float* __restrict__ P,
        float* __restrict__ HLOC) {
    const int d = blockIdx.y * 256 + threadIdx.x;
    const int c = blockIdx.x;
    float Ac[16];
#pragma unroll
    for (int q = 0; q < 4; ++q) {
        float4 v = *(const float4*)(A_log + (size_t)d * 16 + q * 4);
        Ac[q*4+0] = -__expf(v.x); Ac[q*4+1] = -__expf(v.y);
        Ac[q*4+2] = -__expf(v.z); Ac[q*4+3] = -__expf(v.w);
    }
    const float bias = dtb[d];
    float h[16] = {};
    float Pp[16];
#pragma unroll
    for (int s = 0; s < 16; ++s) Pp[s] = 1.f;

    const int t0 = c * CLEN;
    for (int i = 0; i < CLEN; ++i) {
        int t = t0 + i;
        float dtv = softplus_f(DTR[(size_t)t * D_INNER + d] + bias);
        float uu  = U[(size_t)t * D_INNER + d];
        float duu = dtv * uu;
        const float4* xb = (const float4*)(XDBL + (size_t)t * 64 + DT_RANK);
        float4 B0 = xb[0], B1 = xb[1], B2 = xb[2], B3 = xb[3];
        float Bv[16] = {B0.x,B0.y,B0.z,B0.w, B1.x,B1.y,B1.z,B1.w,
                        B2.x,B2.y,B2.z,B2.w, B3.x,B3.y,B3.z,B3.w};
#pragma unroll
        for (int s = 0; s < 16; ++s) {
            float dA = __expf(dtv * Ac[s]);
            h[s] = fmaf(dA, h[s], duu * Bv[s]);
            Pp[s] *= dA;
        }
    }
#pragma unroll
    for (int s = 0; s < 16; ++s) {
        size_t idx = (size_t)c * (D_INNER * D_STATE) + s * D_INNER + d;
        P[idx] = Pp[s];
        HLOC[idx] = h[s];
    }
}

__global__ void scan_pass2(const float* __restrict__ P, float* HLOC) {
    int g = blockIdx.x * 256 + threadIdx.x;          // 0 .. 16383 = (s,d)
    const int STRIDE = D_INNER * D_STATE;
    float h = 0.f;
    for (int c = 0; c < NCHUNK; ++c) {
        float tmp = fmaf(P[(size_t)c * STRIDE + g], h, HLOC[(size_t)c * STRIDE + g]);
        HLOC[(size_t)c * STRIDE + g] = h;            // now holds incoming state
        h = tmp;
    }
}

__global__ void __launch_bounds__(256) scan_pass3(
        const float* __restrict__ DTR, const float* __restrict__ dtb,
        const float* __restrict__ U, const float* __restrict__ XDBL,
        const float* __restrict__ A_log, const float* __restrict__ Dp,
        const float* __restrict__ XZ, const float* __restrict__ HIN,
        float* __restrict__ G) {
    const int d = blockIdx.y * 256 + threadIdx.x;
    const int c = blockIdx.x;
    float Ac[16];
#pragma unroll
    for (int q = 0; q < 4; ++q) {
        float4 v = *(const float4*)(A_log + (size_t)d * 16 + q * 4);
        Ac[q*4+0] = -__expf(v.x); Ac[q*4+1] = -__expf(v.y);
        Ac[q*4+2] = -__expf(v.z); Ac[q*4+3] = -__expf(v.w);
    }
    const float bias = dtb[d];
    const float Dv = Dp[d];
    float h[16];
#pragma unroll
    for (int s = 0; s < 16; ++s)
        h[s] = HIN[(size_t)c * (D_INNER * D_STATE) + s * D_INNER + d];

    const int t0 = c * CLEN;
    for (int i = 0; i < CLEN; ++i) {
        int t = t0 + i;
        float dtv = softplus_f(DTR[(size_t)t * D_INNER + d] + bias);
        float uu  = U[(size_t)t * D_INNER + d];
        float duu = dtv * uu;
        const float4* xb = (const float4*)(XDBL + (size_t)t * 64 + DT_RANK);
        float4 B0 = xb[0], B1 = xb[1], B2 = xb[2], B3 = xb[3];
        float4 C0 = xb[4], C1 = xb[5], C2 = xb[6], C3 = xb[7];
        float Bv[16] = {B0.x,B0.y,B0.z,B0.w, B1.x,B1.y,B1.z,B1.w,
                        B2.x,B2.y,B2.z,B2.w, B3.x,B3.y,B3.z,B3.w};
        float Cv[16] = {C0.x,C0.y,C0.z,C0.w, C1.x,C1.y,C1.z,C1.w,
                        C2.x,C2.y,C2.z,C2.w, C3.x,C3.y,C3.z,C3.w};
        float p = 0.f;
#pragma unroll
        for (int s = 0; s < 16; ++s) {
            float dA = __expf(dtv * Ac[s]);
            h[s] = fmaf(dA, h[s], duu * Bv[s]);
            p = fmaf(h[s], Cv[s], p);
        }
        float y = fmaf(uu, Dv, p);
        float z = XZ[(size_t)t * (2 * D_INNER) + D_INNER + d];
        float sz = z / (1.f + __expf(-z));
        G[(size_t)t * D_INNER + d] = y * sz;
    }
}

// ---------------------------------------------------------------------------
// Attention head
// ---------------------------------------------------------------------------
__global__ void attn_logits(const float* __restrict__ ha, const float* __restrict__ b1,
                            const float* __restrict__ w2, const float* __restrict__ b2,
                            float* __restrict__ logit) {
    int t = blockIdx.x * 256 + threadIdx.x;
    if (t >= L_SEQ) return;
    float acc = b2[0];
#pragma unroll 4
    for (int j = 0; j < ATT_D; ++j)
        acc = fmaf(tanhf(ha[(size_t)t * ATT_D + j] + b1[j]), w2[j], acc);
    logit[t] = acc;
}

__global__ void softmax_weights(const float* __restrict__ logit, float* __restrict__ w) {
    __shared__ float red[256];
    int tid = threadIdx.x;
    float m = -1e30f;
    for (int t = tid; t < L_SEQ; t += 256) m = fmaxf(m, logit[t]);
    red[tid] = m;
    __syncthreads();
    for (int s = 128; s > 0; s >>= 1) {
        if (tid < s) red[tid] = fmaxf(red[tid], red[tid + s]);
        __syncthreads();
    }
    m = red[0];
    __syncthreads();
    float sum = 0.f;
    for (int t = tid; t < L_SEQ; t += 256) sum += __expf(logit[t] - m);
    red[tid] = sum;
    __syncthreads();
    for (int s = 128; s > 0; s >>= 1) {
        if (tid < s) red[tid] += red[tid + s];
        __syncthreads();
    }
    float inv = 1.f / red[0];
    for (int t = tid; t < L_SEQ; t += 256) w[t] = __expf(logit[t] - m) * inv;
}

__global__ void weighted_sum(const float* __restrict__ w, const float* __restrict__ f,
                             float* __restrict__ out) {
    int jl = threadIdx.x & 63, tq = threadIdx.x >> 6;
    int j = blockIdx.x * 64 + jl;
    float acc = 0.f;
    int tbase = blockIdx.y * 512 + tq * 128;
    for (int i = 0; i < 128; ++i) {
        int t = tbase + i;
        acc = fmaf(w[t], f[(size_t)t * D_MODEL + j], acc);
    }
    __shared__ float sred[4][64];
    sred[tq][jl] = acc;
    __syncthreads();
    if (tq == 0)
        atomicAdd(&out[j], sred[0][jl] + sred[1][jl] + sred[2][jl] + sred[3][jl]);
}

// ---------------------------------------------------------------------------
// Host-side orchestration
// ---------------------------------------------------------------------------
extern "C" void kernel_launch(void* const* d_in, const int* in_sizes, int n_in,
                              void* d_out, int out_size, void* d_ws, size_t ws_size,
                              hipStream_t stream) {
    (void)in_sizes; (void)n_in; (void)out_size; (void)ws_size;
    const float* x = (const float*)d_in[0];
    const float* m_in_w[2]   = {(const float*)d_in[1],  (const float*)d_in[10]};
    const float* m_conv_w[2] = {(const float*)d_in[2],  (const float*)d_in[11]};
    const float* m_conv_b[2] = {(const float*)d_in[3],  (const float*)d_in[12]};
    const float* m_xproj[2]  = {(const float*)d_in[4],  (const float*)d_in[13]};
    const float* m_dt_w[2]   = {(const float*)d_in[5],  (const float*)d_in[14]};
    const float* m_dt_b[2]   = {(const float*)d_in[6],  (const float*)d_in[15]};
    const float* m_A_log[2]  = {(const float*)d_in[7],  (const float*)d_in[16]};
    const float* m_D[2]      = {(const float*)d_in[8],  (const float*)d_in[17]};
    const float* m_out_w[2]  = {(const float*)d_in[9],  (const float*)d_in[18]};
    const float* attn_w1 = (const float*)d_in[19];
    const float* attn_b1 = (const float*)d_in[20];
    const float* attn_w2 = (const float*)d_in[21];
    const float* attn_b2 = (const float*)d_in[22];

    const int L = L_SEQ;
    float* ws   = (float*)d_ws;
    float* XZ   = ws;                                  // L*2048
    float* U    = XZ   + (size_t)L * 2048;             // L*1024
    float* XDBL = U    + (size_t)L * 1024;             // L*64
    float* DT   = XDBL + (size_t)L * 64;               // L*1024 (raw, pre-bias)
    float* G    = DT   + (size_t)L * 1024;             // L*1024
    float* F1   = G    + (size_t)L * 1024;             // L*512
    float* P    = F1   + (size_t)L * 512;              // NCHUNK*16384
    float* HLOC = P    + (size_t)NCHUNK * D_INNER * D_STATE;  // NCHUNK*16384
    float* HA   = HLOC + (size_t)NCHUNK * D_INNER * D_STATE;  // L*128
    float* LOGIT= HA   + (size_t)L * ATT_D;            // L
    float* WSM  = LOGIT + L;                           // L
    float* F2   = U;     // U dead after mamba2 scan pass3

    // bf16 / partial overlays on dead regions (lifetimes verified):
    bf16* AaugIn  = (bf16*)G;    // in_gemm input; G written later (pass3)
    bf16* WaugIn  = (bf16*)DT;   // in_gemm weight; DT written later (dt gemm)
    bf16* AaugOut = (bf16*)XZ;   // out_gemm input; XZ dead after pass3
    bf16* WaugOut = (bf16*)DT;   // out_gemm weight; DT dead after pass3
    float* XDBLP  = P;           // split-K partials; P dead until scan1

    auto mamba = [&](const float* inp, int b, float* Fout) {
        // ---- in_proj via bf16x3 MFMA (K'=1536) ----
        split3_act_k<<<(L * 512 + 255) / 256, 256, 0, stream>>>(inp, AaugIn, D_MODEL, L * 512);
        split3_wt_k<<<(2048 * 512 + 255) / 256, 256, 0, stream>>>(m_in_w[b], WaugIn, D_MODEL, 2048 * 512);
        gemm_bf16<128, 128><<<dim3(2048 / 128, L / 128), 256, 0, stream>>>(
            AaugIn, WaugIn, XZ, L, 2 * D_INNER, 3 * D_MODEL);
        // ---- conv + silu ----
        conv_silu_k<<<(L * D_INNER + 255) / 256, 256, 0, stream>>>(XZ, m_conv_w[b], m_conv_b[b], U);
        // ---- xdbl = u @ xproj^T  (split-K=4 fp32) ----
        sgemm<64, 64, 4, 4><<<dim3(1, L / 64, 4), 256, 0, stream>>>(
            U, D_INNER, m_xproj[b], D_INNER, XDBLP, 64, L, 64, D_INNER);
        reduce4_k<<<(L * 64 + 255) / 256, 256, 0, stream>>>(XDBLP, XDBL, L * 64);
        // ---- dt_raw = xdbl[:, :32] @ dt_w^T  (bias+softplus fused in scan) ----
        sgemm<64, 64, 4, 4><<<dim3(D_INNER / 64, L / 64), 256, 0, stream>>>(
            XDBL, 64, m_dt_w[b], DT_RANK, DT, D_INNER, L, D_INNER, DT_RANK);
        // ---- chunked selective scan -> gated G ----
        scan_pass1<<<dim3(NCHUNK, D_INNER / 256), 256, 0, stream>>>(
            DT, m_dt_b[b], U, XDBL, m_A_log[b], P, HLOC);
        scan_pass2<<<(D_INNER * D_STATE) / 256, 256, 0, stream>>>(P, HLOC);
        scan_pass3<<<dim3(NCHUNK, D_INNER / 256), 256, 0, stream>>>(
            DT, m_dt_b[b], U, XDBL, m_A_log[b], m_D[b], XZ, HLOC, G);
        // ---- out_proj via bf16x3 MFMA (K'=3072) ----
        split3_act_k<<<(L * 1024 + 255) / 256, 256, 0, stream>>>(G, AaugOut, D_INNER, L * 1024);
        split3_wt_k<<<(512 * 1024 + 255) / 256, 256, 0, stream>>>(m_out_w[b], WaugOut, D_INNER, 512 * 1024);
        gemm_bf16<64, 128><<<dim3(512 / 128, L / 64), 256, 0, stream>>>(
            AaugOut, WaugOut, Fout, L, D_MODEL, 3 * D_INNER);
    };

    mamba(x, 0, F1);
    mamba(F1, 1, F2);

    // attention
    sgemm<64, 64, 4, 4><<<dim3(ATT_D / 64, L / 64), 256, 0, stream>>>(
        x, D_MODEL, attn_w1, D_MODEL, HA, ATT_D, L, ATT_D, D_MODEL);
    attn_logits<<<(L + 255) / 256, 256, 0, stream>>>(HA, attn_b1, attn_w2, attn_b2, LOGIT);
    softmax_weights<<<1, 256, 0, stream>>>(LOGIT, WSM);
    hipMemsetAsync(d_out, 0, D_MODEL * sizeof(float), stream);
    weighted_sum<<<dim3(D_MODEL / 64, 8), 256, 0, stream>>>(WSM, F2, (float*)d_out);
}

// Round 4
// 582.556 us; speedup vs baseline: 1.9017x; 1.1628x over previous
//
#include <hip/hip_runtime.h>
#include <cstddef>
#include <cstdint>

// ---------------------------------------------------------------------------
// Problem constants
// ---------------------------------------------------------------------------
#define L_SEQ   4096
#define D_MODEL 512
#define D_INNER 1024
#define D_STATE 16
#define DT_RANK 32
#define ATT_D   128
#define NCHUNK  128    // 128 chunks x 32 steps = 4096
#define CLEN    32

typedef __bf16 bf16;
typedef __bf16 bf16x8 __attribute__((ext_vector_type(8)));
typedef float  f32x4  __attribute__((ext_vector_type(4)));

__device__ __forceinline__ void load_lds16(const void* g, void* l) {
    __builtin_amdgcn_global_load_lds(
        (const __attribute__((address_space(1))) uint32_t*)g,
        (__attribute__((address_space(3))) uint32_t*)l, 16, 0, 0);
}

// ---------------------------------------------------------------------------
// bf16 MFMA GEMM, single-barrier double-buffered K-loop.
// C[M,N] = A[M,K] * B[N,K]^T (fp32 out). Optional split-K (NSPLIT slabs of
// M*ldc at C0) and dual output planes (col < csplit -> C0 else C1).
// ---------------------------------------------------------------------------
template <int BM, int BN, int NSPLIT>
__global__ void __launch_bounds__(256) gemm_bf16(const bf16* __restrict__ A,
                                                 const bf16* __restrict__ B,
                                                 float* __restrict__ C0,
                                                 float* __restrict__ C1,
                                                 int csplit, int ldc,
                                                 int M, int N, int K) {
    constexpr int BK = 32;
    constexpr int TM = BM / 32;
    constexpr int TN = BN / 32;
    __shared__ bf16 As[2][BM][BK];
    __shared__ bf16 Bs[2][BN][BK];
    const int tid  = threadIdx.x;
    const int lane = tid & 63;
    const int wid  = tid >> 6;
    const int wm   = wid >> 1;
    const int wn   = wid & 1;
    const int m_l  = lane & 15;
    const int quad = lane >> 4;
    const int row0 = blockIdx.y * BM;
    const int col0 = blockIdx.x * BN;
    const int ar = tid >> 2;
    const int ac = (tid & 3) * 8;

    const int kper = K / NSPLIT;
    const int kbeg = blockIdx.z * kper;
    const int iters = kper / BK;

    f32x4 acc[TM][TN] = {};

    auto stage = [&](int k0, int buf) {
#pragma unroll
        for (int r = 0; r < BM / 64; ++r)
            load_lds16(A + (size_t)(row0 + ar + r * 64) * K + k0 + ac,
                       (char*)&As[buf][0][0] + (tid + r * 256) * 16);
#pragma unroll
        for (int r = 0; r < BN / 64; ++r)
            load_lds16(B + (size_t)(col0 + ar + r * 64) * K + k0 + ac,
                       (char*)&Bs[buf][0][0] + (tid + r * 256) * 16);
    };

    stage(kbeg, 0);
    for (int it = 0; it < iters; ++it) {
        int cur = it & 1;
        __syncthreads();                 // drains prefetch for 'cur'
        if (it + 1 < iters) stage(kbeg + (it + 1) * BK, cur ^ 1);

        bf16x8 af[TM], bfr[TN];
#pragma unroll
        for (int i = 0; i < TM; ++i)
            af[i] = *(const bf16x8*)&As[cur][wm * (BM / 2) + i * 16 + m_l][quad * 8];
#pragma unroll
        for (int j = 0; j < TN; ++j)
            bfr[j] = *(const bf16x8*)&Bs[cur][wn * (BN / 2) + j * 16 + m_l][quad * 8];
#pragma unroll
        for (int i = 0; i < TM; ++i)
#pragma unroll
            for (int j = 0; j < TN; ++j)
                acc[i][j] = __builtin_amdgcn_mfma_f32_16x16x32_bf16(
                                af[i], bfr[j], acc[i][j], 0, 0, 0);
    }
    // C/D layout: col = lane&15, row = quad*4 + reg
#pragma unroll
    for (int i = 0; i < TM; ++i)
#pragma unroll
        for (int j = 0; j < TN; ++j) {
            int rr = row0 + wm * (BM / 2) + i * 16 + quad * 4;
            int cc = col0 + wn * (BN / 2) + j * 16 + m_l;
            float* base; int c2;
            if (cc < csplit) { base = C0; c2 = cc; }
            else             { base = C1; c2 = cc - csplit; }
            base += (size_t)blockIdx.z * (size_t)M * ldc;
#pragma unroll
            for (int g = 0; g < 4; ++g)
                base[(size_t)(rr + g) * ldc + c2] = acc[i][j][g];
        }
}

// ---------------------------------------------------------------------------
// fp32 -> augmented bf16 splits.  act rows: [hi|lo|hi]   wt rows: [hi|hi|lo]
// ---------------------------------------------------------------------------
__global__ void split3_act_k(const float* __restrict__ X, bf16* __restrict__ Y,
                             int K, int total) {
    int i = blockIdx.x * 256 + threadIdx.x;
    if (i >= total) return;
    int row = i / K, col = i - row * K;
    float v = X[i];
    bf16 h = (bf16)v;
    bf16 l = (bf16)(v - (float)h);
    bf16* yr = Y + (size_t)row * 3 * K;
    yr[col] = h; yr[K + col] = l; yr[2 * K + col] = h;
}

__global__ void split3_wt_k(const float* __restrict__ X, bf16* __restrict__ Y,
                            int K, int total) {
    int i = blockIdx.x * 256 + threadIdx.x;
    if (i >= total) return;
    int row = i / K, col = i - row * K;
    float v = X[i];
    bf16 h = (bf16)v;
    bf16 l = (bf16)(v - (float)h);
    bf16* yr = Y + (size_t)row * 3 * K;
    yr[col] = h; yr[K + col] = h; yr[2 * K + col] = l;
}

// ---------------------------------------------------------------------------
// fp32 SGEMM (small GEMMs), optional split-K via gridDim.z.
// ---------------------------------------------------------------------------
template <int BM, int BN, int TM, int TN>
__global__ void __launch_bounds__(256) sgemm(const float* __restrict__ A, int lda,
                                             const float* __restrict__ B, int ldb,
                                             float* __restrict__ C, int ldc,
                                             int M, int N, int K) {
    constexpr int BK = 16;
    __shared__ float As[BK][BM + 4];
    __shared__ float Bs[BK][BN + 4];
    const int tid = threadIdx.x;
    const int tx = tid & 15;
    const int ty = tid >> 4;
    const int row0 = blockIdx.y * BM;
    const int col0 = blockIdx.x * BN;
    const int nz = gridDim.z;
    const int kper = K / nz;
    const int kbeg = blockIdx.z * kper, kend = kbeg + kper;
    float* Cz = C + (size_t)blockIdx.z * M * ldc;

    float acc[TM][TN] = {};

    for (int k0 = kbeg; k0 < kend; k0 += BK) {
#pragma unroll
        for (int i = 0; i < (BM * BK) / (256 * 4); ++i) {
            int lin = tid + i * 256;
            int m = lin >> 2;
            int kk = (lin & 3) << 2;
            float4 v = *(const float4*)(A + (size_t)(row0 + m) * lda + k0 + kk);
            As[kk + 0][m] = v.x; As[kk + 1][m] = v.y;
            As[kk + 2][m] = v.z; As[kk + 3][m] = v.w;
        }
#pragma unroll
        for (int i = 0; i < (BN * BK) / (256 * 4); ++i) {
            int lin = tid + i * 256;
            int m = lin >> 2;
            int kk = (lin & 3) << 2;
            float4 v = *(const float4*)(B + (size_t)(col0 + m) * ldb + k0 + kk);
            Bs[kk + 0][m] = v.x; Bs[kk + 1][m] = v.y;
            Bs[kk + 2][m] = v.z; Bs[kk + 3][m] = v.w;
        }
        __syncthreads();
#pragma unroll
        for (int k = 0; k < BK; ++k) {
            float a[TM], b[TN];
#pragma unroll
            for (int i = 0; i < TM; ++i) a[i] = As[k][ty * TM + i];
#pragma unroll
            for (int j = 0; j < TN; ++j) b[j] = Bs[k][tx * TN + j];
#pragma unroll
            for (int i = 0; i < TM; ++i)
#pragma unroll
                for (int j = 0; j < TN; ++j)
                    acc[i][j] = fmaf(a[i], b[j], acc[i][j]);
        }
        __syncthreads();
    }
#pragma unroll
    for (int i = 0; i < TM; ++i) {
        size_t r = (size_t)(row0 + ty * TM + i);
#pragma unroll
        for (int j = 0; j < TN; ++j)
            Cz[r * ldc + col0 + tx * TN + j] = acc[i][j];
    }
}

__global__ void reduce4_k(const float* __restrict__ Pp, float* __restrict__ Y, int n) {
    int i = blockIdx.x * 256 + threadIdx.x;
    if (i >= n) return;
    Y[i] = (Pp[i] + Pp[i + n]) + (Pp[i + 2 * n] + Pp[i + 3 * n]);
}

// Sum 2 split-K slabs; optionally write fp32 Y and/or augmented bf16 (K=512).
__global__ void reduce2_aug_k(const float* __restrict__ Pp, float* __restrict__ Y,
                              bf16* __restrict__ Aaug, int n) {
    int i = blockIdx.x * 256 + threadIdx.x;
    if (i >= n) return;
    float v = Pp[i] + Pp[i + n];
    if (Y) Y[i] = v;
    if (Aaug) {
        int row = i >> 9, col = i & 511;
        bf16 h = (bf16)v;
        bf16 l = (bf16)(v - (float)h);
        bf16* r = Aaug + (size_t)row * 1536;
        r[col] = h; r[512 + col] = l; r[1024 + col] = h;
    }
}

// ---------------------------------------------------------------------------
// Depthwise causal conv (k=4) + bias + silu.  XIN plane [L, 1024].
// ---------------------------------------------------------------------------
__global__ void conv_silu_k(const float* __restrict__ XIN, const float* __restrict__ cw,
                            const float* __restrict__ cb, float* __restrict__ U) {
    int i = blockIdx.x * 256 + threadIdx.x;
    if (i >= L_SEQ * D_INNER) return;
    int t = i >> 10;
    int d = i & (D_INNER - 1);
    float acc = cb[d];
#pragma unroll
    for (int k = 0; k < 4; ++k) {
        int tt = t - 3 + k;
        if (tt >= 0) acc = fmaf(cw[d * 4 + k], XIN[(size_t)tt * D_INNER + d], acc);
    }
    U[i] = acc / (1.f + __expf(-acc));
}

// ---------------------------------------------------------------------------
// Chunked selective scan, channel-per-lane; dt GEMM (K=32) + bias + softplus
// fused inline.  pass3 writes the augmented bf16 A-operand for out_proj.
// ---------------------------------------------------------------------------
__device__ __forceinline__ float softplus_f(float v) {
    return (v > 20.f) ? v : log1pf(__expf(v));
}

__global__ void __launch_bounds__(256) scan_pass1(
        const float* __restrict__ U, const float* __restrict__ XDBL,
        const float* __restrict__ dt_w, const float* __restrict__ dtb,
        const float* __restrict__ A_log, float* __restrict__ P,
        float* __restrict__ HLOC) {
    const int d = blockIdx.y * 256 + threadIdx.x;
    const int c = blockIdx.x;
    float Ac[16];
#pragma unroll
    for (int q = 0; q < 4; ++q) {
        float4 v = *(const float4*)(A_log + (size_t)d * 16 + q * 4);
        Ac[q*4+0] = -__expf(v.x); Ac[q*4+1] = -__expf(v.y);
        Ac[q*4+2] = -__expf(v.z); Ac[q*4+3] = -__expf(v.w);
    }
    float wdt[32];
#pragma unroll
    for (int q = 0; q < 8; ++q) {
        float4 v = *(const float4*)(dt_w + (size_t)d * 32 + q * 4);
        wdt[q*4+0] = v.x; wdt[q*4+1] = v.y; wdt[q*4+2] = v.z; wdt[q*4+3] = v.w;
    }
    const float bias = dtb[d];
    float h[16] = {};
    float Pp[16];
#pragma unroll
    for (int s = 0; s < 16; ++s) Pp[s] = 1.f;

    const int t0 = c * CLEN;
    for (int i = 0; i < CLEN; ++i) {
        int t = t0 + i;
        const float4* xr = (const float4*)(XDBL + (size_t)t * 64);
        float dot = bias;
#pragma unroll
        for (int q = 0; q < 8; ++q) {
            float4 v = xr[q];
            dot = fmaf(v.x, wdt[q*4+0], dot); dot = fmaf(v.y, wdt[q*4+1], dot);
            dot = fmaf(v.z, wdt[q*4+2], dot); dot = fmaf(v.w, wdt[q*4+3], dot);
        }
        float dtv = softplus_f(dot);
        float uu  = U[(size_t)t * D_INNER + d];
        float duu = dtv * uu;
        float4 B0 = xr[8], B1 = xr[9], B2 = xr[10], B3 = xr[11];
        float Bv[16] = {B0.x,B0.y,B0.z,B0.w, B1.x,B1.y,B1.z,B1.w,
                        B2.x,B2.y,B2.z,B2.w, B3.x,B3.y,B3.z,B3.w};
#pragma unroll
        for (int s = 0; s < 16; ++s) {
            float dA = __expf(dtv * Ac[s]);
            h[s] = fmaf(dA, h[s], duu * Bv[s]);
            Pp[s] *= dA;
        }
    }
#pragma unroll
    for (int s = 0; s < 16; ++s) {
        size_t idx = (size_t)c * (D_INNER * D_STATE) + s * D_INNER + d;
        P[idx] = Pp[s];
        HLOC[idx] = h[s];
    }
}

__global__ void scan_pass2(const float* __restrict__ P, float* HLOC) {
    int g = blockIdx.x * 256 + threadIdx.x;
    const int STRIDE = D_INNER * D_STATE;
    float h = 0.f;
    for (int c = 0; c < NCHUNK; ++c) {
        float tmp = fmaf(P[(size_t)c * STRIDE + g], h, HLOC[(size_t)c * STRIDE + g]);
        HLOC[(size_t)c * STRIDE + g] = h;     // now holds incoming state
        h = tmp;
    }
}

__global__ void __launch_bounds__(256) scan_pass3(
        const float* __restrict__ U, const float* __restrict__ XDBL,
        const float* __restrict__ dt_w, const float* __restrict__ dtb,
        const float* __restrict__ A_log, const float* __restrict__ Dp,
        const float* __restrict__ Z, const float* __restrict__ HIN,
        bf16* __restrict__ Aaug) {
    const int d = blockIdx.y * 256 + threadIdx.x;
    const int c = blockIdx.x;
    float Ac[16];
#pragma unroll
    for (int q = 0; q < 4; ++q) {
        float4 v = *(const float4*)(A_log + (size_t)d * 16 + q * 4);
        Ac[q*4+0] = -__expf(v.x); Ac[q*4+1] = -__expf(v.y);
        Ac[q*4+2] = -__expf(v.z); Ac[q*4+3] = -__expf(v.w);
    }
    float wdt[32];
#pragma unroll
    for (int q = 0; q < 8; ++q) {
        float4 v = *(const float4*)(dt_w + (size_t)d * 32 + q * 4);
        wdt[q*4+0] = v.x; wdt[q*4+1] = v.y; wdt[q*4+2] = v.z; wdt[q*4+3] = v.w;
    }
    const float bias = dtb[d];
    const float Dv = Dp[d];
    float h[16];
#pragma unroll
    for (int s = 0; s < 16; ++s)
        h[s] = HIN[(size_t)c * (D_INNER * D_STATE) + s * D_INNER + d];

    const int t0 = c * CLEN;
    for (int i = 0; i < CLEN; ++i) {
        int t = t0 + i;
        const float4* xr = (const float4*)(XDBL + (size_t)t * 64);
        float dot = bias;
#pragma unroll
        for (int q = 0; q < 8; ++q) {
            float4 v = xr[q];
            dot = fmaf(v.x, wdt[q*4+0], dot); dot = fmaf(v.y, wdt[q*4+1], dot);
            dot = fmaf(v.z, wdt[q*4+2], dot); dot = fmaf(v.w, wdt[q*4+3], dot);
        }
        float dtv = softplus_f(dot);
        float uu  = U[(size_t)t * D_INNER + d];
        float duu = dtv * uu;
        float4 B0 = xr[8],  B1 = xr[9],  B2 = xr[10], B3 = xr[11];
        float4 C0 = xr[12], C1 = xr[13], C2 = xr[14], C3 = xr[15];
        float Bv[16] = {B0.x,B0.y,B0.z,B0.w, B1.x,B1.y,B1.z,B1.w,
                        B2.x,B2.y,B2.z,B2.w, B3.x,B3.y,B3.z,B3.w};
        float Cv[16] = {C0.x,C0.y,C0.z,C0.w, C1.x,C1.y,C1.z,C1.w,
                        C2.x,C2.y,C2.z,C2.w, C3.x,C3.y,C3.z,C3.w};
        float p = 0.f;
#pragma unroll
        for (int s = 0; s < 16; ++s) {
            float dA = __expf(dtv * Ac[s]);
            h[s] = fmaf(dA, h[s], duu * Bv[s]);
            p = fmaf(h[s], Cv[s], p);
        }
        float y = fmaf(uu, Dv, p);
        float z = Z[(size_t)t * D_INNER + d];
        float sz = z / (1.f + __expf(-z));
        float g = y * sz;
        bf16 hi = (bf16)g;
        bf16 lo = (bf16)(g - (float)hi);
        bf16* row = Aaug + (size_t)t * 3072;
        row[d] = hi; row[1024 + d] = lo; row[2048 + d] = hi;
    }
}

// ---------------------------------------------------------------------------
// Attention head.  |logit| <= sum|w2| (+|b2|) ~ 5 (tanh-bounded) -> safe to
// skip the max-subtraction pass.
// ---------------------------------------------------------------------------
__global__ void attn_logits_exp(const float* __restrict__ ha, const float* __restrict__ b1,
                                const float* __restrict__ w2, const float* __restrict__ b2,
                                float* __restrict__ E, float* __restrict__ Sp) {
    int t = blockIdx.x * 256 + threadIdx.x;
    float acc = b2[0];
#pragma unroll 4
    for (int j = 0; j < ATT_D; ++j)
        acc = fmaf(tanhf(ha[(size_t)t * ATT_D + j] + b1[j]), w2[j], acc);
    float e = __expf(acc);
    E[t] = e;
    __shared__ float red[256];
    int tid = threadIdx.x;
    red[tid] = e;
    __syncthreads();
    for (int s = 128; s > 0; s >>= 1) {
        if (tid < s) red[tid] += red[tid + s];
        __syncthreads();
    }
    if (tid == 0) Sp[blockIdx.x] = red[0];
}

// out[j] = sum_t (E[t]/S) * f[t, j]
__global__ void weighted_sum(const float* __restrict__ E, const float* __restrict__ Sp,
                             const float* __restrict__ f, float* __restrict__ out) {
    float S = 0.f;
#pragma unroll
    for (int k = 0; k < 16; ++k) S += Sp[k];
    int jl = threadIdx.x & 63, tq = threadIdx.x >> 6;
    int j = blockIdx.x * 64 + jl;
    float acc = 0.f;
    int tbase = blockIdx.y * 512 + tq * 128;
    for (int i = 0; i < 128; ++i) {
        int t = tbase + i;
        acc = fmaf(E[t], f[(size_t)t * D_MODEL + j], acc);
    }
    __shared__ float sred[4][64];
    sred[tq][jl] = acc;
    __syncthreads();
    if (tq == 0)
        atomicAdd(&out[j], (sred[0][jl] + sred[1][jl] + sred[2][jl] + sred[3][jl]) / S);
}

// ---------------------------------------------------------------------------
// Host-side orchestration
// ---------------------------------------------------------------------------
extern "C" void kernel_launch(void* const* d_in, const int* in_sizes, int n_in,
                              void* d_out, int out_size, void* d_ws, size_t ws_size,
                              hipStream_t stream) {
    (void)in_sizes; (void)n_in; (void)out_size; (void)ws_size;
    const float* x = (const float*)d_in[0];
    const float* m_in_w[2]   = {(const float*)d_in[1],  (const float*)d_in[10]};
    const float* m_conv_w[2] = {(const float*)d_in[2],  (const float*)d_in[11]};
    const float* m_conv_b[2] = {(const float*)d_in[3],  (const float*)d_in[12]};
    const float* m_xproj[2]  = {(const float*)d_in[4],  (const float*)d_in[13]};
    const float* m_dt_w[2]   = {(const float*)d_in[5],  (const float*)d_in[14]};
    const float* m_dt_b[2]   = {(const float*)d_in[6],  (const float*)d_in[15]};
    const float* m_A_log[2]  = {(const float*)d_in[7],  (const float*)d_in[16]};
    const float* m_D[2]      = {(const float*)d_in[8],  (const float*)d_in[17]};
    const float* m_out_w[2]  = {(const float*)d_in[9],  (const float*)d_in[18]};
    const float* attn_w1 = (const float*)d_in[19];
    const float* attn_b1 = (const float*)d_in[20];
    const float* attn_w2 = (const float*)d_in[21];
    const float* attn_b2 = (const float*)d_in[22];

    const int L = L_SEQ;
    float* ws = (float*)d_ws;
    // Regions (floats); overlays noted.
    float* XIN   = ws;                                   // L*1024; AaugOut head
    float* AUXA  = XIN  + (size_t)L * 1024;              // 2,097,152 ; AaugOut tail
    float* Z     = AUXA + 2097152;                       // L*1024; OutP overlay
    float* U     = Z    + (size_t)L * 1024;              // L*1024; F2 overlay
    float* XDBL  = U    + (size_t)L * 1024;              // L*64
    float* FREG  = XDBL + (size_t)L * 64;                // 3,145,728: AaugIn / HA+E+Sp
    float* W1i   = FREG + 3145728;                       // WaugIn1  1,572,864
    float* W1o   = W1i  + 1572864;                       // WaugOut1   786,432
    float* W2i   = W1o  + 786432;                        // WaugIn2  1,572,864
    float* W2o   = W2i  + 1572864;                       // WaugOut2   786,432
    float* P     = W2o  + 786432;                        // NCHUNK*16384; XDBLP overlay
    float* HLOC  = P    + (size_t)NCHUNK * D_INNER * D_STATE;

    bf16* AaugOut = (bf16*)XIN;    // [L,3072] bf16 = XIN+AUXA (XIN dead after conv)
    bf16* AaugIn  = (bf16*)FREG;   // [L,1536] bf16
    bf16* WaugIn[2]  = {(bf16*)W1i, (bf16*)W2i};
    bf16* WaugOut[2] = {(bf16*)W1o, (bf16*)W2o};
    float* XDBLP = P;              // 4 x L*64 split-K partials (pre-scan)
    float* OutP  = Z;              // 2 x L*512 split-K partials (post-pass3)
    float* F2    = U;              // mamba2 output (post-pass3)
    float* HA    = FREG;           // attention hidden [L,128]
    float* E     = FREG + 524288;  // exp(logits) [L]
    float* Sp    = E + L;          // 16 partial sums

    // ---- pre-split all weights ----
    split3_wt_k<<<(2048 * 512 + 255) / 256, 256, 0, stream>>>(m_in_w[0], WaugIn[0], 512, 2048 * 512);
    split3_wt_k<<<(512 * 1024 + 255) / 256, 256, 0, stream>>>(m_out_w[0], WaugOut[0], 1024, 512 * 1024);
    split3_wt_k<<<(2048 * 512 + 255) / 256, 256, 0, stream>>>(m_in_w[1], WaugIn[1], 512, 2048 * 512);
    split3_wt_k<<<(512 * 1024 + 255) / 256, 256, 0, stream>>>(m_out_w[1], WaugOut[1], 1024, 512 * 1024);
    // ---- x -> augmented bf16 ----
    split3_act_k<<<(L * 512 + 255) / 256, 256, 0, stream>>>(x, AaugIn, 512, L * 512);

    auto mamba = [&](int b, float* FoutY, bf16* FoutAug) {
        // in_proj: [XIN|Z] = AaugIn @ WaugIn^T   (M=L, N=2048, K'=1536)
        gemm_bf16<128, 128, 1><<<dim3(16, 32, 1), 256, 0, stream>>>(
            AaugIn, WaugIn[b], XIN, Z, 1024, 1024, L, 2048, 1536);
        conv_silu_k<<<(L * D_INNER + 255) / 256, 256, 0, stream>>>(XIN, m_conv_w[b], m_conv_b[b], U);
        // xdbl = U @ xproj^T  (split-K=4)
        sgemm<64, 64, 4, 4><<<dim3(1, L / 64, 4), 256, 0, stream>>>(
            U, D_INNER, m_xproj[b], D_INNER, XDBLP, 64, L, 64, D_INNER);
        reduce4_k<<<(L * 64 + 255) / 256, 256, 0, stream>>>(XDBLP, XDBL, L * 64);
        // chunked scan (dt GEMM fused inline); pass3 emits augmented bf16
        scan_pass1<<<dim3(NCHUNK, 4), 256, 0, stream>>>(
            U, XDBL, m_dt_w[b], m_dt_b[b], m_A_log[b], P, HLOC);
        scan_pass2<<<(D_INNER * D_STATE) / 256, 256, 0, stream>>>(P, HLOC);
        scan_pass3<<<dim3(NCHUNK, 4), 256, 0, stream>>>(
            U, XDBL, m_dt_w[b], m_dt_b[b], m_A_log[b], m_D[b], Z, HLOC, AaugOut);
        // out_proj: split-K=2  (M=L, N=512, K'=3072)
        gemm_bf16<64, 128, 2><<<dim3(4, 64, 2), 256, 0, stream>>>(
            AaugOut, WaugOut[b], OutP, nullptr, 512, 512, L, 512, 3072);
        reduce2_aug_k<<<(L * 512 + 255) / 256, 256, 0, stream>>>(OutP, FoutY, FoutAug, L * 512);
    };

    mamba(0, nullptr, AaugIn);   // mamba1 -> next block's augmented input
    mamba(1, F2, nullptr);       // mamba2 -> F2 fp32

    // attention
    sgemm<64, 64, 4, 4><<<dim3(ATT_D / 64, L / 64, 1), 256, 0, stream>>>(
        x, D_MODEL, attn_w1, D_MODEL, HA, ATT_D, L, ATT_D, D_MODEL);
    attn_logits_exp<<<L / 256, 256, 0, stream>>>(HA, attn_b1, attn_w2, attn_b2, E, Sp);
    hipMemsetAsync(d_out, 0, D_MODEL * sizeof(float), stream);
    weighted_sum<<<dim3(D_MODEL / 64, 8), 256, 0, stream>>>(E, Sp, F2, (float*)d_out);
}

// Round 5
// 568.806 us; speedup vs baseline: 1.9476x; 1.0242x over previous
//
#include <hip/hip_runtime.h>
#include <cstddef>
#include <cstdint>

// ---------------------------------------------------------------------------
// Problem constants
// ---------------------------------------------------------------------------
#define L_SEQ   4096
#define D_MODEL 512
#define D_INNER 1024
#define D_STATE 16
#define DT_RANK 32
#define ATT_D   128
#define NCHUNK  128    // 128 chunks x 32 steps = 4096
#define CLEN    32

typedef __bf16 bf16;
typedef __bf16 bf16x8 __attribute__((ext_vector_type(8)));
typedef float  f32x4  __attribute__((ext_vector_type(4)));

__device__ __forceinline__ void load_lds16(const void* g, void* l) {
    __builtin_amdgcn_global_load_lds(
        (const __attribute__((address_space(1))) uint32_t*)g,
        (__attribute__((address_space(3))) uint32_t*)l, 16, 0, 0);
}

// ---------------------------------------------------------------------------
// bf16 MFMA GEMM, single-barrier double-buffered K-loop.
// C[M,N] = A[M,K] * B[N,K]^T (fp32 out). Optional split-K (NSPLIT slabs of
// M*ldc at the C base) and dual output planes (col < csplit -> C0 else C1).
// ---------------------------------------------------------------------------
template <int BM, int BN, int NSPLIT>
__global__ void __launch_bounds__(256) gemm_bf16(const bf16* __restrict__ A,
                                                 const bf16* __restrict__ B,
                                                 float* __restrict__ C0,
                                                 float* __restrict__ C1,
                                                 int csplit, int ldc,
                                                 int M, int N, int K) {
    constexpr int BK = 32;
    constexpr int TM = BM / 32;
    constexpr int TN = BN / 32;
    __shared__ bf16 As[2][BM][BK];
    __shared__ bf16 Bs[2][BN][BK];
    const int tid  = threadIdx.x;
    const int lane = tid & 63;
    const int wid  = tid >> 6;
    const int wm   = wid >> 1;
    const int wn   = wid & 1;
    const int m_l  = lane & 15;
    const int quad = lane >> 4;
    const int row0 = blockIdx.y * BM;
    const int col0 = blockIdx.x * BN;
    const int ar = tid >> 2;
    const int ac = (tid & 3) * 8;

    const int kper = K / NSPLIT;
    const int kbeg = blockIdx.z * kper;
    const int iters = kper / BK;

    f32x4 acc[TM][TN] = {};

    auto stage = [&](int k0, int buf) {
#pragma unroll
        for (int r = 0; r < BM / 64; ++r)
            load_lds16(A + (size_t)(row0 + ar + r * 64) * K + k0 + ac,
                       (char*)&As[buf][0][0] + (tid + r * 256) * 16);
#pragma unroll
        for (int r = 0; r < BN / 64; ++r)
            load_lds16(B + (size_t)(col0 + ar + r * 64) * K + k0 + ac,
                       (char*)&Bs[buf][0][0] + (tid + r * 256) * 16);
    };

    stage(kbeg, 0);
    for (int it = 0; it < iters; ++it) {
        int cur = it & 1;
        __syncthreads();                 // drains prefetch for 'cur'
        if (it + 1 < iters) stage(kbeg + (it + 1) * BK, cur ^ 1);

        bf16x8 af[TM], bfr[TN];
#pragma unroll
        for (int i = 0; i < TM; ++i)
            af[i] = *(const bf16x8*)&As[cur][wm * (BM / 2) + i * 16 + m_l][quad * 8];
#pragma unroll
        for (int j = 0; j < TN; ++j)
            bfr[j] = *(const bf16x8*)&Bs[cur][wn * (BN / 2) + j * 16 + m_l][quad * 8];
#pragma unroll
        for (int i = 0; i < TM; ++i)
#pragma unroll
            for (int j = 0; j < TN; ++j)
                acc[i][j] = __builtin_amdgcn_mfma_f32_16x16x32_bf16(
                                af[i], bfr[j], acc[i][j], 0, 0, 0);
    }
    // C/D layout: col = lane&15, row = quad*4 + reg
#pragma unroll
    for (int i = 0; i < TM; ++i)
#pragma unroll
        for (int j = 0; j < TN; ++j) {
            int rr = row0 + wm * (BM / 2) + i * 16 + quad * 4;
            int cc = col0 + wn * (BN / 2) + j * 16 + m_l;
            float* base; int c2;
            if (cc < csplit) { base = C0; c2 = cc; }
            else             { base = C1; c2 = cc - csplit; }
            base += (size_t)blockIdx.z * (size_t)M * ldc;
#pragma unroll
            for (int g = 0; g < 4; ++g)
                base[(size_t)(rr + g) * ldc + c2] = acc[i][j][g];
        }
}

// ---------------------------------------------------------------------------
// One-launch weight/activation splitting into augmented bf16.
// wt rows: [hi|hi|lo]  act rows: [hi|lo|hi]
// Segments: in_w0 (2048x512 wt), out_w0 (512x1024 wt), in_w1, out_w1,
//           x (4096x512 act).
// ---------------------------------------------------------------------------
#define N_INW  (2048 * 512)
#define N_OUTW (512 * 1024)
#define N_X    (4096 * 512)

__global__ void split_all_k(const float* __restrict__ in_w0, const float* __restrict__ out_w0,
                            const float* __restrict__ in_w1, const float* __restrict__ out_w1,
                            const float* __restrict__ x,
                            bf16* __restrict__ Win0, bf16* __restrict__ Wout0,
                            bf16* __restrict__ Win1, bf16* __restrict__ Wout1,
                            bf16* __restrict__ Ax) {
    int i = blockIdx.x * 256 + threadIdx.x;
    const float* src; bf16* dst; int K; int act = 0;
    if (i < N_INW)                  { src = in_w0;  dst = Win0;  K = 512; }
    else if ((i -= N_INW) < N_OUTW) { src = out_w0; dst = Wout0; K = 1024; }
    else if ((i -= N_OUTW) < N_INW) { src = in_w1;  dst = Win1;  K = 512; }
    else if ((i -= N_INW) < N_OUTW) { src = out_w1; dst = Wout1; K = 1024; }
    else if ((i -= N_OUTW) < N_X)   { src = x;      dst = Ax;    K = 512; act = 1; }
    else return;
    int row = i / K, col = i - row * K;
    float v = src[i];
    bf16 h = (bf16)v;
    bf16 l = (bf16)(v - (float)h);
    bf16* yr = dst + (size_t)row * 3 * K;
    if (act) { yr[col] = h; yr[K + col] = l; yr[2 * K + col] = h; }
    else     { yr[col] = h; yr[K + col] = h; yr[2 * K + col] = l; }
}

// ---------------------------------------------------------------------------
// fp32 SGEMM (small GEMMs), split-K via gridDim.z.
// ---------------------------------------------------------------------------
template <int BM, int BN, int TM, int TN>
__global__ void __launch_bounds__(256) sgemm(const float* __restrict__ A, int lda,
                                             const float* __restrict__ B, int ldb,
                                             float* __restrict__ C, int ldc,
                                             int M, int N, int K) {
    constexpr int BK = 16;
    __shared__ float As[BK][BM + 4];
    __shared__ float Bs[BK][BN + 4];
    const int tid = threadIdx.x;
    const int tx = tid & 15;
    const int ty = tid >> 4;
    const int row0 = blockIdx.y * BM;
    const int col0 = blockIdx.x * BN;
    const int nz = gridDim.z;
    const int kper = K / nz;
    const int kbeg = blockIdx.z * kper, kend = kbeg + kper;
    float* Cz = C + (size_t)blockIdx.z * M * ldc;

    float acc[TM][TN] = {};

    for (int k0 = kbeg; k0 < kend; k0 += BK) {
#pragma unroll
        for (int i = 0; i < (BM * BK) / (256 * 4); ++i) {
            int lin = tid + i * 256;
            int m = lin >> 2;
            int kk = (lin & 3) << 2;
            float4 v = *(const float4*)(A + (size_t)(row0 + m) * lda + k0 + kk);
            As[kk + 0][m] = v.x; As[kk + 1][m] = v.y;
            As[kk + 2][m] = v.z; As[kk + 3][m] = v.w;
        }
#pragma unroll
        for (int i = 0; i < (BN * BK) / (256 * 4); ++i) {
            int lin = tid + i * 256;
            int m = lin >> 2;
            int kk = (lin & 3) << 2;
            float4 v = *(const float4*)(B + (size_t)(col0 + m) * ldb + k0 + kk);
            Bs[kk + 0][m] = v.x; Bs[kk + 1][m] = v.y;
            Bs[kk + 2][m] = v.z; Bs[kk + 3][m] = v.w;
        }
        __syncthreads();
#pragma unroll
        for (int k = 0; k < BK; ++k) {
            float a[TM], b[TN];
#pragma unroll
            for (int i = 0; i < TM; ++i) a[i] = As[k][ty * TM + i];
#pragma unroll
            for (int j = 0; j < TN; ++j) b[j] = Bs[k][tx * TN + j];
#pragma unroll
            for (int i = 0; i < TM; ++i)
#pragma unroll
                for (int j = 0; j < TN; ++j)
                    acc[i][j] = fmaf(a[i], b[j], acc[i][j]);
        }
        __syncthreads();
    }
#pragma unroll
    for (int i = 0; i < TM; ++i) {
        size_t r = (size_t)(row0 + ty * TM + i);
#pragma unroll
        for (int j = 0; j < TN; ++j)
            Cz[r * ldc + col0 + tx * TN + j] = acc[i][j];
    }
}

// Sum nslab split-K slabs; optional fp32 Y and/or augmented bf16 (width 512).
__global__ void reduce_aug_k(const float* __restrict__ Pp, float* __restrict__ Y,
                             bf16* __restrict__ Aaug, int n, int nslab) {
    int i = blockIdx.x * 256 + threadIdx.x;
    if (i >= n) return;
    float v = 0.f;
    for (int k = 0; k < nslab; ++k) v += Pp[(size_t)k * n + i];
    if (Y) Y[i] = v;
    if (Aaug) {
        int row = i >> 9, col = i & 511;
        bf16 h = (bf16)v;
        bf16 l = (bf16)(v - (float)h);
        bf16* r = Aaug + (size_t)row * 1536;
        r[col] = h; r[512 + col] = l; r[1024 + col] = h;
    }
}

// ---------------------------------------------------------------------------
// Depthwise causal conv (k=4) + bias + silu.  XIN plane [L, 1024].
// ---------------------------------------------------------------------------
__global__ void conv_silu_k(const float* __restrict__ XIN, const float* __restrict__ cw,
                            const float* __restrict__ cb, float* __restrict__ U) {
    int i = blockIdx.x * 256 + threadIdx.x;
    if (i >= L_SEQ * D_INNER) return;
    int t = i >> 10;
    int d = i & (D_INNER - 1);
    float acc = cb[d];
#pragma unroll
    for (int k = 0; k < 4; ++k) {
        int tt = t - 3 + k;
        if (tt >= 0) acc = fmaf(cw[d * 4 + k], XIN[(size_t)tt * D_INNER + d], acc);
    }
    U[i] = acc / (1.f + __expf(-acc));
}

// ---------------------------------------------------------------------------
// Chunked selective scan, channel-per-lane; dt GEMM (K=32) + bias + softplus
// fused inline.  pass3 writes the augmented bf16 A-operand for out_proj.
// ---------------------------------------------------------------------------
__device__ __forceinline__ float softplus_f(float v) {
    return (v > 20.f) ? v : log1pf(__expf(v));
}

__global__ void __launch_bounds__(256) scan_pass1(
        const float* __restrict__ U, const float* __restrict__ XDBL,
        const float* __restrict__ dt_w, const float* __restrict__ dtb,
        const float* __restrict__ A_log, float* __restrict__ P,
        float* __restrict__ HLOC) {
    const int d = blockIdx.y * 256 + threadIdx.x;
    const int c = blockIdx.x;
    float Ac[16];
#pragma unroll
    for (int q = 0; q < 4; ++q) {
        float4 v = *(const float4*)(A_log + (size_t)d * 16 + q * 4);
        Ac[q*4+0] = -__expf(v.x); Ac[q*4+1] = -__expf(v.y);
        Ac[q*4+2] = -__expf(v.z); Ac[q*4+3] = -__expf(v.w);
    }
    float wdt[32];
#pragma unroll
    for (int q = 0; q < 8; ++q) {
        float4 v = *(const float4*)(dt_w + (size_t)d * 32 + q * 4);
        wdt[q*4+0] = v.x; wdt[q*4+1] = v.y; wdt[q*4+2] = v.z; wdt[q*4+3] = v.w;
    }
    const float bias = dtb[d];
    float h[16] = {};
    float Pp[16];
#pragma unroll
    for (int s = 0; s < 16; ++s) Pp[s] = 1.f;

    const int t0 = c * CLEN;
    for (int i = 0; i < CLEN; ++i) {
        int t = t0 + i;
        const float4* xr = (const float4*)(XDBL + (size_t)t * 64);
        float dot = bias;
#pragma unroll
        for (int q = 0; q < 8; ++q) {
            float4 v = xr[q];
            dot = fmaf(v.x, wdt[q*4+0], dot); dot = fmaf(v.y, wdt[q*4+1], dot);
            dot = fmaf(v.z, wdt[q*4+2], dot); dot = fmaf(v.w, wdt[q*4+3], dot);
        }
        float dtv = softplus_f(dot);
        float uu  = U[(size_t)t * D_INNER + d];
        float duu = dtv * uu;
        float4 B0 = xr[8], B1 = xr[9], B2 = xr[10], B3 = xr[11];
        float Bv[16] = {B0.x,B0.y,B0.z,B0.w, B1.x,B1.y,B1.z,B1.w,
                        B2.x,B2.y,B2.z,B2.w, B3.x,B3.y,B3.z,B3.w};
#pragma unroll
        for (int s = 0; s < 16; ++s) {
            float dA = __expf(dtv * Ac[s]);
            h[s] = fmaf(dA, h[s], duu * Bv[s]);
            Pp[s] *= dA;
        }
    }
#pragma unroll
    for (int s = 0; s < 16; ++s) {
        size_t idx = (size_t)c * (D_INNER * D_STATE) + s * D_INNER + d;
        P[idx] = Pp[s];
        HLOC[idx] = h[s];
    }
}

__global__ void scan_pass2(const float* __restrict__ P, float* HLOC) {
    int g = blockIdx.x * 256 + threadIdx.x;
    const int STRIDE = D_INNER * D_STATE;
    float h = 0.f;
    for (int c = 0; c < NCHUNK; ++c) {
        float tmp = fmaf(P[(size_t)c * STRIDE + g], h, HLOC[(size_t)c * STRIDE + g]);
        HLOC[(size_t)c * STRIDE + g] = h;     // now holds incoming state
        h = tmp;
    }
}

__global__ void __launch_bounds__(256) scan_pass3(
        const float* __restrict__ U, const float* __restrict__ XDBL,
        const float* __restrict__ dt_w, const float* __restrict__ dtb,
        const float* __restrict__ A_log, const float* __restrict__ Dp,
        const float* __restrict__ Z, const float* __restrict__ HIN,
        bf16* __restrict__ Aaug) {
    const int d = blockIdx.y * 256 + threadIdx.x;
    const int c = blockIdx.x;
    float Ac[16];
#pragma unroll
    for (int q = 0; q < 4; ++q) {
        float4 v = *(const float4*)(A_log + (size_t)d * 16 + q * 4);
        Ac[q*4+0] = -__expf(v.x); Ac[q*4+1] = -__expf(v.y);
        Ac[q*4+2] = -__expf(v.z); Ac[q*4+3] = -__expf(v.w);
    }
    float wdt[32];
#pragma unroll
    for (int q = 0; q < 8; ++q) {
        float4 v = *(const float4*)(dt_w + (size_t)d * 32 + q * 4);
        wdt[q*4+0] = v.x; wdt[q*4+1] = v.y; wdt[q*4+2] = v.z; wdt[q*4+3] = v.w;
    }
    const float bias = dtb[d];
    const float Dv = Dp[d];
    float h[16];
#pragma unroll
    for (int s = 0; s < 16; ++s)
        h[s] = HIN[(size_t)c * (D_INNER * D_STATE) + s * D_INNER + d];

    const int t0 = c * CLEN;
    for (int i = 0; i < CLEN; ++i) {
        int t = t0 + i;
        const float4* xr = (const float4*)(XDBL + (size_t)t * 64);
        float dot = bias;
#pragma unroll
        for (int q = 0; q < 8; ++q) {
            float4 v = xr[q];
            dot = fmaf(v.x, wdt[q*4+0], dot); dot = fmaf(v.y, wdt[q*4+1], dot);
            dot = fmaf(v.z, wdt[q*4+2], dot); dot = fmaf(v.w, wdt[q*4+3], dot);
        }
        float dtv = softplus_f(dot);
        float uu  = U[(size_t)t * D_INNER + d];
        float duu = dtv * uu;
        float4 B0 = xr[8],  B1 = xr[9],  B2 = xr[10], B3 = xr[11];
        float4 C0 = xr[12], C1 = xr[13], C2 = xr[14], C3 = xr[15];
        float Bv[16] = {B0.x,B0.y,B0.z,B0.w, B1.x,B1.y,B1.z,B1.w,
                        B2.x,B2.y,B2.z,B2.w, B3.x,B3.y,B3.z,B3.w};
        float Cv[16] = {C0.x,C0.y,C0.z,C0.w, C1.x,C1.y,C1.z,C1.w,
                        C2.x,C2.y,C2.z,C2.w, C3.x,C3.y,C3.z,C3.w};
        float p = 0.f;
#pragma unroll
        for (int s = 0; s < 16; ++s) {
            float dA = __expf(dtv * Ac[s]);
            h[s] = fmaf(dA, h[s], duu * Bv[s]);
            p = fmaf(h[s], Cv[s], p);
        }
        float y = fmaf(uu, Dv, p);
        float z = Z[(size_t)t * D_INNER + d];
        float sz = z / (1.f + __expf(-z));
        float g = y * sz;
        bf16 hi = (bf16)g;
        bf16 lo = (bf16)(g - (float)hi);
        bf16* row = Aaug + (size_t)t * 3072;
        row[d] = hi; row[1024 + d] = lo; row[2048 + d] = hi;
    }
}

// ---------------------------------------------------------------------------
// Attention head.  |logit| <= sum|w2| (+|b2|) ~ 5 (tanh-bounded) -> safe to
// skip the max-subtraction pass.
// ---------------------------------------------------------------------------
__global__ void attn_logits_exp(const float* __restrict__ ha, const float* __restrict__ b1,
                                const float* __restrict__ w2, const float* __restrict__ b2,
                                float* __restrict__ E, float* __restrict__ Sp) {
    int t = blockIdx.x * 256 + threadIdx.x;
    float acc = b2[0];
#pragma unroll 4
    for (int j = 0; j < ATT_D; ++j)
        acc = fmaf(tanhf(ha[(size_t)t * ATT_D + j] + b1[j]), w2[j], acc);
    float e = __expf(acc);
    E[t] = e;
    __shared__ float red[256];
    int tid = threadIdx.x;
    red[tid] = e;
    __syncthreads();
    for (int s = 128; s > 0; s >>= 1) {
        if (tid < s) red[tid] += red[tid + s];
        __syncthreads();
    }
    if (tid == 0) Sp[blockIdx.x] = red[0];
}

// out[j] = sum_t (E[t]/S) * f[t, j]
__global__ void weighted_sum(const float* __restrict__ E, const float* __restrict__ Sp,
                             const float* __restrict__ f, float* __restrict__ out) {
    float S = 0.f;
#pragma unroll
    for (int k = 0; k < 16; ++k) S += Sp[k];
    int jl = threadIdx.x & 63, tq = threadIdx.x >> 6;
    int j = blockIdx.x * 64 + jl;
    float acc = 0.f;
    int tbase = blockIdx.y * 512 + tq * 128;
    for (int i = 0; i < 128; ++i) {
        int t = tbase + i;
        acc = fmaf(E[t], f[(size_t)t * D_MODEL + j], acc);
    }
    __shared__ float sred[4][64];
    sred[tq][jl] = acc;
    __syncthreads();
    if (tq == 0)
        atomicAdd(&out[j], (sred[0][jl] + sred[1][jl] + sred[2][jl] + sred[3][jl]) / S);
}

// ---------------------------------------------------------------------------
// Host-side orchestration
// ---------------------------------------------------------------------------
extern "C" void kernel_launch(void* const* d_in, const int* in_sizes, int n_in,
                              void* d_out, int out_size, void* d_ws, size_t ws_size,
                              hipStream_t stream) {
    (void)in_sizes; (void)n_in; (void)out_size; (void)ws_size;
    const float* x = (const float*)d_in[0];
    const float* m_in_w[2]   = {(const float*)d_in[1],  (const float*)d_in[10]};
    const float* m_conv_w[2] = {(const float*)d_in[2],  (const float*)d_in[11]};
    const float* m_conv_b[2] = {(const float*)d_in[3],  (const float*)d_in[12]};
    const float* m_xproj[2]  = {(const float*)d_in[4],  (const float*)d_in[13]};
    const float* m_dt_w[2]   = {(const float*)d_in[5],  (const float*)d_in[14]};
    const float* m_dt_b[2]   = {(const float*)d_in[6],  (const float*)d_in[15]};
    const float* m_A_log[2]  = {(const float*)d_in[7],  (const float*)d_in[16]};
    const float* m_D[2]      = {(const float*)d_in[8],  (const float*)d_in[17]};
    const float* m_out_w[2]  = {(const float*)d_in[9],  (const float*)d_in[18]};
    const float* attn_w1 = (const float*)d_in[19];
    const float* attn_b1 = (const float*)d_in[20];
    const float* attn_w2 = (const float*)d_in[21];
    const float* attn_b2 = (const float*)d_in[22];

    const int L = L_SEQ;
    float* ws = (float*)d_ws;
    // Regions (floats); overlays noted.
    float* XIN   = ws;                                   // L*1024; AaugOut head
    float* AUXA  = XIN  + (size_t)L * 1024;              // 2,097,152 ; AaugOut tail
    float* Z     = AUXA + 2097152;                       // L*1024; OutP slab 0-1
    float* U     = Z    + (size_t)L * 1024;              // L*1024; OutP slab 2-3
    float* XDBL  = U    + (size_t)L * 1024;              // L*64
    float* FREG  = XDBL + (size_t)L * 64;                // 3,145,728: AaugIn / F2+HA+E+Sp
    float* W1i   = FREG + 3145728;                       // WaugIn1  1,572,864
    float* W1o   = W1i  + 1572864;                       // WaugOut1   786,432
    float* W2i   = W1o  + 786432;                        // WaugIn2  1,572,864
    float* W2o   = W2i  + 1572864;                       // WaugOut2   786,432
    float* P     = W2o  + 786432;                        // 2,097,152; partials overlay
    float* HLOC  = P    + (size_t)NCHUNK * D_INNER * D_STATE;

    bf16* AaugOut = (bf16*)XIN;    // [L,3072] bf16 spans XIN+AUXA
    bf16* AaugIn  = (bf16*)FREG;   // [L,1536] bf16
    bf16* WaugIn[2]  = {(bf16*)W1i, (bf16*)W2i};
    bf16* WaugOut[2] = {(bf16*)W1o, (bf16*)W2o};
    float* XDBLP = P;              // 8 x L*64 split-K partials (pre-scan)
    float* OutP  = Z;              // 4 x L*512 split-K partials (post-pass3; Z+U dead)
    float* F2    = FREG;           // mamba2 output [L,512] (AaugIn dead by then)
    float* HA    = FREG + 2097152; // attention hidden [L,128]
    float* HAP   = P;              // 4 x L*128 attn split-K partials (P dead post-mamba2)
    float* E     = HA + 524288;    // exp(logits) [L]
    float* Sp    = E + L;          // 16 partial sums

    // ---- all weight/x splits in one launch ----
    split_all_k<<<(2 * N_INW + 2 * N_OUTW + N_X) / 256, 256, 0, stream>>>(
        m_in_w[0], m_out_w[0], m_in_w[1], m_out_w[1], x,
        WaugIn[0], WaugOut[0], WaugIn[1], WaugOut[1], AaugIn);

    auto mamba = [&](int b, float* FoutY, bf16* FoutAug) {
        // in_proj: [XIN|Z] = AaugIn @ WaugIn^T   (M=L, N=2048, K'=1536)
        gemm_bf16<128, 64, 1><<<dim3(32, 32, 1), 256, 0, stream>>>(
            AaugIn, WaugIn[b], XIN, Z, 1024, 1024, L, 2048, 1536);
        conv_silu_k<<<(L * D_INNER + 255) / 256, 256, 0, stream>>>(XIN, m_conv_w[b], m_conv_b[b], U);
        // xdbl = U @ xproj^T  (split-K=8)
        sgemm<64, 64, 4, 4><<<dim3(1, L / 64, 8), 256, 0, stream>>>(
            U, D_INNER, m_xproj[b], D_INNER, XDBLP, 64, L, 64, D_INNER);
        reduce_aug_k<<<(L * 64 + 255) / 256, 256, 0, stream>>>(XDBLP, XDBL, nullptr, L * 64, 8);
        // chunked scan (dt GEMM fused inline); pass3 emits augmented bf16
        scan_pass1<<<dim3(NCHUNK, 4), 256, 0, stream>>>(
            U, XDBL, m_dt_w[b], m_dt_b[b], m_A_log[b], P, HLOC);
        scan_pass2<<<(D_INNER * D_STATE) / 256, 256, 0, stream>>>(P, HLOC);
        scan_pass3<<<dim3(NCHUNK, 4), 256, 0, stream>>>(
            U, XDBL, m_dt_w[b], m_dt_b[b], m_A_log[b], m_D[b], Z, HLOC, AaugOut);
        // out_proj: split-K=4  (M=L, N=512, K'=3072), partials on dead Z+U
        gemm_bf16<64, 128, 4><<<dim3(4, 64, 4), 256, 0, stream>>>(
            AaugOut, WaugOut[b], OutP, nullptr, 512, 512, L, 512, 3072);
        reduce_aug_k<<<(L * 512 + 255) / 256, 256, 0, stream>>>(OutP, FoutY, FoutAug, L * 512, 4);
    };

    mamba(0, nullptr, AaugIn);   // mamba1 -> next block's augmented input
    mamba(1, F2, nullptr);       // mamba2 -> F2 fp32

    // attention: HA = x @ w1^T  (split-K=4)
    sgemm<64, 64, 4, 4><<<dim3(ATT_D / 64, L / 64, 4), 256, 0, stream>>>(
        x, D_MODEL, attn_w1, D_MODEL, HAP, ATT_D, L, ATT_D, D_MODEL);
    reduce_aug_k<<<(L * ATT_D + 255) / 256, 256, 0, stream>>>(HAP, HA, nullptr, L * ATT_D, 4);
    attn_logits_exp<<<L / 256, 256, 0, stream>>>(HA, attn_b1, attn_w2, attn_b2, E, Sp);
    hipMemsetAsync(d_out, 0, D_MODEL * sizeof(float), stream);
    weighted_sum<<<dim3(D_MODEL / 64, 8), 256, 0, stream>>>(E, Sp, F2, (float*)d_out);
}

// Round 6
// 567.314 us; speedup vs baseline: 1.9528x; 1.0026x over previous
//
#include <hip/hip_runtime.h>
#include <cstddef>
#include <cstdint>

// ---------------------------------------------------------------------------
// Problem constants
// ---------------------------------------------------------------------------
#define L_SEQ   4096
#define D_MODEL 512
#define D_INNER 1024
#define D_STATE 16
#define DT_RANK 32
#define ATT_D   128
#define NCHUNK  128    // 128 chunks x 32 steps = 4096
#define CLEN    32

typedef __bf16 bf16;
typedef __bf16 bf16x8 __attribute__((ext_vector_type(8)));
typedef float  f32x4  __attribute__((ext_vector_type(4)));

__device__ __forceinline__ void load_lds16(const void* g, void* l) {
    __builtin_amdgcn_global_load_lds(
        (const __attribute__((address_space(1))) uint32_t*)g,
        (__attribute__((address_space(3))) uint32_t*)l, 16, 0, 0);
}

// ---------------------------------------------------------------------------
// bf16 MFMA GEMM, single-barrier double-buffered K-loop, XOR-swizzled LDS.
// C[M,N] = A[M,K] * B[N,K]^T (fp32 out). Optional split-K (NSPLIT slabs of
// M*ldc at the C base) and dual output planes (col < csplit -> C0 else C1).
//
// LDS layout: row-major [rows][BK], but the 16B chunk position within a row
// is p = chunk ^ ((row>>1)&3).  Staging permutes the GLOBAL source address
// (legal: global_load_lds dest is fixed lane-linear; the permutation stays
// within each 64B row-slice so cacheline traffic is unchanged).  Fragment
// reads then hit all 32 banks with exactly 2-way aliasing (free, m136).
// ---------------------------------------------------------------------------
template <int BM, int BN, int NSPLIT>
__global__ void __launch_bounds__(256) gemm_bf16(const bf16* __restrict__ A,
                                                 const bf16* __restrict__ B,
                                                 float* __restrict__ C0,
                                                 float* __restrict__ C1,
                                                 int csplit, int ldc,
                                                 int M, int N, int K) {
    constexpr int BK = 32;
    constexpr int TM = BM / 32;
    constexpr int TN = BN / 32;
    __shared__ bf16 As[2][BM][BK];
    __shared__ bf16 Bs[2][BN][BK];
    const int tid  = threadIdx.x;
    const int lane = tid & 63;
    const int wid  = tid >> 6;
    const int wm   = wid >> 1;
    const int wn   = wid & 1;
    const int m_l  = lane & 15;
    const int quad = lane >> 4;
    const int row0 = blockIdx.y * BM;
    const int col0 = blockIdx.x * BN;

    const int kper = K / NSPLIT;
    const int kbeg = blockIdx.z * kper;
    const int iters = kper / BK;

    f32x4 acc[TM][TN] = {};

    auto stage = [&](int k0, int buf) {
#pragma unroll
        for (int r = 0; r < BM / 64; ++r) {
            int sl  = tid + r * 256;            // 16B slot = row*4 + pos
            int row = sl >> 2;
            int ch  = (sl & 3) ^ ((row >> 1) & 3);   // logical chunk at this pos
            load_lds16(A + (size_t)(row0 + row) * K + k0 + ch * 8,
                       (char*)&As[buf][0][0] + sl * 16);
        }
#pragma unroll
        for (int r = 0; r < BN / 64; ++r) {
            int sl  = tid + r * 256;
            int row = sl >> 2;
            int ch  = (sl & 3) ^ ((row >> 1) & 3);
            load_lds16(B + (size_t)(col0 + row) * K + k0 + ch * 8,
                       (char*)&Bs[buf][0][0] + sl * 16);
        }
    };

    stage(kbeg, 0);
    for (int it = 0; it < iters; ++it) {
        int cur = it & 1;
        __syncthreads();                 // drains prefetch for 'cur'
        if (it + 1 < iters) stage(kbeg + (it + 1) * BK, cur ^ 1);

        bf16x8 af[TM], bfr[TN];
#pragma unroll
        for (int i = 0; i < TM; ++i) {
            int r = wm * (BM / 2) + i * 16 + m_l;
            af[i] = *(const bf16x8*)&As[cur][r][(quad ^ ((r >> 1) & 3)) * 8];
        }
#pragma unroll
        for (int j = 0; j < TN; ++j) {
            int r = wn * (BN / 2) + j * 16 + m_l;
            bfr[j] = *(const bf16x8*)&Bs[cur][r][(quad ^ ((r >> 1) & 3)) * 8];
        }
#pragma unroll
        for (int i = 0; i < TM; ++i)
#pragma unroll
            for (int j = 0; j < TN; ++j)
                acc[i][j] = __builtin_amdgcn_mfma_f32_16x16x32_bf16(
                                af[i], bfr[j], acc[i][j], 0, 0, 0);
    }
    // C/D layout: col = lane&15, row = quad*4 + reg
#pragma unroll
    for (int i = 0; i < TM; ++i)
#pragma unroll
        for (int j = 0; j < TN; ++j) {
            int rr = row0 + wm * (BM / 2) + i * 16 + quad * 4;
            int cc = col0 + wn * (BN / 2) + j * 16 + m_l;
            float* base; int c2;
            if (cc < csplit) { base = C0; c2 = cc; }
            else             { base = C1; c2 = cc - csplit; }
            base += (size_t)blockIdx.z * (size_t)M * ldc;
#pragma unroll
            for (int g = 0; g < 4; ++g)
                base[(size_t)(rr + g) * ldc + c2] = acc[i][j][g];
        }
}

// ---------------------------------------------------------------------------
// One-launch weight/activation splitting into augmented bf16.
// wt rows: [hi|hi|lo]  act rows: [hi|lo|hi]
// ---------------------------------------------------------------------------
#define N_INW  (2048 * 512)
#define N_OUTW (512 * 1024)
#define N_X    (4096 * 512)

__global__ void split_all_k(const float* __restrict__ in_w0, const float* __restrict__ out_w0,
                            const float* __restrict__ in_w1, const float* __restrict__ out_w1,
                            const float* __restrict__ x,
                            bf16* __restrict__ Win0, bf16* __restrict__ Wout0,
                            bf16* __restrict__ Win1, bf16* __restrict__ Wout1,
                            bf16* __restrict__ Ax) {
    int i = blockIdx.x * 256 + threadIdx.x;
    const float* src; bf16* dst; int K; int act = 0;
    if (i < N_INW)                  { src = in_w0;  dst = Win0;  K = 512; }
    else if ((i -= N_INW) < N_OUTW) { src = out_w0; dst = Wout0; K = 1024; }
    else if ((i -= N_OUTW) < N_INW) { src = in_w1;  dst = Win1;  K = 512; }
    else if ((i -= N_INW) < N_OUTW) { src = out_w1; dst = Wout1; K = 1024; }
    else if ((i -= N_OUTW) < N_X)   { src = x;      dst = Ax;    K = 512; act = 1; }
    else return;
    int row = i / K, col = i - row * K;
    float v = src[i];
    bf16 h = (bf16)v;
    bf16 l = (bf16)(v - (float)h);
    bf16* yr = dst + (size_t)row * 3 * K;
    if (act) { yr[col] = h; yr[K + col] = l; yr[2 * K + col] = h; }
    else     { yr[col] = h; yr[K + col] = h; yr[2 * K + col] = l; }
}

// ---------------------------------------------------------------------------
// fp32 SGEMM (small GEMMs), split-K via gridDim.z.
// ---------------------------------------------------------------------------
template <int BM, int BN, int TM, int TN>
__global__ void __launch_bounds__(256) sgemm(const float* __restrict__ A, int lda,
                                             const float* __restrict__ B, int ldb,
                                             float* __restrict__ C, int ldc,
                                             int M, int N, int K) {
    constexpr int BK = 16;
    __shared__ float As[BK][BM + 4];
    __shared__ float Bs[BK][BN + 4];
    const int tid = threadIdx.x;
    const int tx = tid & 15;
    const int ty = tid >> 4;
    const int row0 = blockIdx.y * BM;
    const int col0 = blockIdx.x * BN;
    const int nz = gridDim.z;
    const int kper = K / nz;
    const int kbeg = blockIdx.z * kper, kend = kbeg + kper;
    float* Cz = C + (size_t)blockIdx.z * M * ldc;

    float acc[TM][TN] = {};

    for (int k0 = kbeg; k0 < kend; k0 += BK) {
#pragma unroll
        for (int i = 0; i < (BM * BK) / (256 * 4); ++i) {
            int lin = tid + i * 256;
            int m = lin >> 2;
            int kk = (lin & 3) << 2;
            float4 v = *(const float4*)(A + (size_t)(row0 + m) * lda + k0 + kk);
            As[kk + 0][m] = v.x; As[kk + 1][m] = v.y;
            As[kk + 2][m] = v.z; As[kk + 3][m] = v.w;
        }
#pragma unroll
        for (int i = 0; i < (BN * BK) / (256 * 4); ++i) {
            int lin = tid + i * 256;
            int m = lin >> 2;
            int kk = (lin & 3) << 2;
            float4 v = *(const float4*)(B + (size_t)(col0 + m) * ldb + k0 + kk);
            Bs[kk + 0][m] = v.x; Bs[kk + 1][m] = v.y;
            Bs[kk + 2][m] = v.z; Bs[kk + 3][m] = v.w;
        }
        __syncthreads();
#pragma unroll
        for (int k = 0; k < BK; ++k) {
            float a[TM], b[TN];
#pragma unroll
            for (int i = 0; i < TM; ++i) a[i] = As[k][ty * TM + i];
#pragma unroll
            for (int j = 0; j < TN; ++j) b[j] = Bs[k][tx * TN + j];
#pragma unroll
            for (int i = 0; i < TM; ++i)
#pragma unroll
                for (int j = 0; j < TN; ++j)
                    acc[i][j] = fmaf(a[i], b[j], acc[i][j]);
        }
        __syncthreads();
    }
#pragma unroll
    for (int i = 0; i < TM; ++i) {
        size_t r = (size_t)(row0 + ty * TM + i);
#pragma unroll
        for (int j = 0; j < TN; ++j)
            Cz[r * ldc + col0 + tx * TN + j] = acc[i][j];
    }
}

// Sum nslab split-K slabs; optional fp32 Y and/or augmented bf16 (width 512).
__global__ void reduce_aug_k(const float* __restrict__ Pp, float* __restrict__ Y,
                             bf16* __restrict__ Aaug, int n, int nslab) {
    int i = blockIdx.x * 256 + threadIdx.x;
    if (i >= n) return;
    float v = 0.f;
    for (int k = 0; k < nslab; ++k) v += Pp[(size_t)k * n + i];
    if (Y) Y[i] = v;
    if (Aaug) {
        int row = i >> 9, col = i & 511;
        bf16 h = (bf16)v;
        bf16 l = (bf16)(v - (float)h);
        bf16* r = Aaug + (size_t)row * 1536;
        r[col] = h; r[512 + col] = l; r[1024 + col] = h;
    }
}

// ---------------------------------------------------------------------------
// Depthwise causal conv (k=4) + bias + silu.  XIN plane [L, 1024].
// ---------------------------------------------------------------------------
__global__ void conv_silu_k(const float* __restrict__ XIN, const float* __restrict__ cw,
                            const float* __restrict__ cb, float* __restrict__ U) {
    int i = blockIdx.x * 256 + threadIdx.x;
    if (i >= L_SEQ * D_INNER) return;
    int t = i >> 10;
    int d = i & (D_INNER - 1);
    float acc = cb[d];
#pragma unroll
    for (int k = 0; k < 4; ++k) {
        int tt = t - 3 + k;
        if (tt >= 0) acc = fmaf(cw[d * 4 + k], XIN[(size_t)tt * D_INNER + d], acc);
    }
    U[i] = acc / (1.f + __expf(-acc));
}

// ---------------------------------------------------------------------------
// Chunked selective scan, channel-per-lane; dt GEMM (K=32) + bias + softplus
// fused inline.  pass3 writes the augmented bf16 A-operand for out_proj.
// ---------------------------------------------------------------------------
__device__ __forceinline__ float softplus_f(float v) {
    return (v > 20.f) ? v : log1pf(__expf(v));
}

__global__ void __launch_bounds__(256) scan_pass1(
        const float* __restrict__ U, const float* __restrict__ XDBL,
        const float* __restrict__ dt_w, const float* __restrict__ dtb,
        const float* __restrict__ A_log, float* __restrict__ P,
        float* __restrict__ HLOC) {
    const int d = blockIdx.y * 256 + threadIdx.x;
    const int c = blockIdx.x;
    float Ac[16];
#pragma unroll
    for (int q = 0; q < 4; ++q) {
        float4 v = *(const float4*)(A_log + (size_t)d * 16 + q * 4);
        Ac[q*4+0] = -__expf(v.x); Ac[q*4+1] = -__expf(v.y);
        Ac[q*4+2] = -__expf(v.z); Ac[q*4+3] = -__expf(v.w);
    }
    float wdt[32];
#pragma unroll
    for (int q = 0; q < 8; ++q) {
        float4 v = *(const float4*)(dt_w + (size_t)d * 32 + q * 4);
        wdt[q*4+0] = v.x; wdt[q*4+1] = v.y; wdt[q*4+2] = v.z; wdt[q*4+3] = v.w;
    }
    const float bias = dtb[d];
    float h[16] = {};
    float Pp[16];
#pragma unroll
    for (int s = 0; s < 16; ++s) Pp[s] = 1.f;

    const int t0 = c * CLEN;
    for (int i = 0; i < CLEN; ++i) {
        int t = t0 + i;
        const float4* xr = (const float4*)(XDBL + (size_t)t * 64);
        float dot = bias;
#pragma unroll
        for (int q = 0; q < 8; ++q) {
            float4 v = xr[q];
            dot = fmaf(v.x, wdt[q*4+0], dot); dot = fmaf(v.y, wdt[q*4+1], dot);
            dot = fmaf(v.z, wdt[q*4+2], dot); dot = fmaf(v.w, wdt[q*4+3], dot);
        }
        float dtv = softplus_f(dot);
        float uu  = U[(size_t)t * D_INNER + d];
        float duu = dtv * uu;
        float4 B0 = xr[8], B1 = xr[9], B2 = xr[10], B3 = xr[11];
        float Bv[16] = {B0.x,B0.y,B0.z,B0.w, B1.x,B1.y,B1.z,B1.w,
                        B2.x,B2.y,B2.z,B2.w, B3.x,B3.y,B3.z,B3.w};
#pragma unroll
        for (int s = 0; s < 16; ++s) {
            float dA = __expf(dtv * Ac[s]);
            h[s] = fmaf(dA, h[s], duu * Bv[s]);
            Pp[s] *= dA;
        }
    }
#pragma unroll
    for (int s = 0; s < 16; ++s) {
        size_t idx = (size_t)c * (D_INNER * D_STATE) + s * D_INNER + d;
        P[idx] = Pp[s];
        HLOC[idx] = h[s];
    }
}

__global__ void scan_pass2(const float* __restrict__ P, float* HLOC) {
    int g = blockIdx.x * 256 + threadIdx.x;
    const int STRIDE = D_INNER * D_STATE;
    float h = 0.f;
    for (int c = 0; c < NCHUNK; ++c) {
        float tmp = fmaf(P[(size_t)c * STRIDE + g], h, HLOC[(size_t)c * STRIDE + g]);
        HLOC[(size_t)c * STRIDE + g] = h;     // now holds incoming state
        h = tmp;
    }
}

__global__ void __launch_bounds__(256) scan_pass3(
        const float* __restrict__ U, const float* __restrict__ XDBL,
        const float* __restrict__ dt_w, const float* __restrict__ dtb,
        const float* __restrict__ A_log, const float* __restrict__ Dp,
        const float* __restrict__ Z, const float* __restrict__ HIN,
        bf16* __restrict__ Aaug) {
    const int d = blockIdx.y * 256 + threadIdx.x;
    const int c = blockIdx.x;
    float Ac[16];
#pragma unroll
    for (int q = 0; q < 4; ++q) {
        float4 v = *(const float4*)(A_log + (size_t)d * 16 + q * 4);
        Ac[q*4+0] = -__expf(v.x); Ac[q*4+1] = -__expf(v.y);
        Ac[q*4+2] = -__expf(v.z); Ac[q*4+3] = -__expf(v.w);
    }
    float wdt[32];
#pragma unroll
    for (int q = 0; q < 8; ++q) {
        float4 v = *(const float4*)(dt_w + (size_t)d * 32 + q * 4);
        wdt[q*4+0] = v.x; wdt[q*4+1] = v.y; wdt[q*4+2] = v.z; wdt[q*4+3] = v.w;
    }
    const float bias = dtb[d];
    const float Dv = Dp[d];
    float h[16];
#pragma unroll
    for (int s = 0; s < 16; ++s)
        h[s] = HIN[(size_t)c * (D_INNER * D_STATE) + s * D_INNER + d];

    const int t0 = c * CLEN;
    for (int i = 0; i < CLEN; ++i) {
        int t = t0 + i;
        const float4* xr = (const float4*)(XDBL + (size_t)t * 64);
        float dot = bias;
#pragma unroll
        for (int q = 0; q < 8; ++q) {
            float4 v = xr[q];
            dot = fmaf(v.x, wdt[q*4+0], dot); dot = fmaf(v.y, wdt[q*4+1], dot);
            dot = fmaf(v.z, wdt[q*4+2], dot); dot = fmaf(v.w, wdt[q*4+3], dot);
        }
        float dtv = softplus_f(dot);
        float uu  = U[(size_t)t * D_INNER + d];
        float duu = dtv * uu;
        float4 B0 = xr[8],  B1 = xr[9],  B2 = xr[10], B3 = xr[11];
        float4 C0 = xr[12], C1 = xr[13], C2 = xr[14], C3 = xr[15];
        float Bv[16] = {B0.x,B0.y,B0.z,B0.w, B1.x,B1.y,B1.z,B1.w,
                        B2.x,B2.y,B2.z,B2.w, B3.x,B3.y,B3.z,B3.w};
        float Cv[16] = {C0.x,C0.y,C0.z,C0.w, C1.x,C1.y,C1.z,C1.w,
                        C2.x,C2.y,C2.z,C2.w, C3.x,C3.y,C3.z,C3.w};
        float p = 0.f;
#pragma unroll
        for (int s = 0; s < 16; ++s) {
            float dA = __expf(dtv * Ac[s]);
            h[s] = fmaf(dA, h[s], duu * Bv[s]);
            p = fmaf(h[s], Cv[s], p);
        }
        float y = fmaf(uu, Dv, p);
        float z = Z[(size_t)t * D_INNER + d];
        float sz = z / (1.f + __expf(-z));
        float g = y * sz;
        bf16 hi = (bf16)g;
        bf16 lo = (bf16)(g - (float)hi);
        bf16* row = Aaug + (size_t)t * 3072;
        row[d] = hi; row[1024 + d] = lo; row[2048 + d] = hi;
    }
}

// ---------------------------------------------------------------------------
// Attention head.  |logit| <= sum|w2| (+|b2|) ~ 5 (tanh-bounded) -> safe to
// skip the max-subtraction pass.
// ---------------------------------------------------------------------------
__global__ void attn_logits_exp(const float* __restrict__ ha, const float* __restrict__ b1,
                                const float* __restrict__ w2, const float* __restrict__ b2,
                                float* __restrict__ E, float* __restrict__ Sp) {
    int t = blockIdx.x * 256 + threadIdx.x;
    float acc = b2[0];
#pragma unroll 4
    for (int j = 0; j < ATT_D; ++j)
        acc = fmaf(tanhf(ha[(size_t)t * ATT_D + j] + b1[j]), w2[j], acc);
    float e = __expf(acc);
    E[t] = e;
    __shared__ float red[256];
    int tid = threadIdx.x;
    red[tid] = e;
    __syncthreads();
    for (int s = 128; s > 0; s >>= 1) {
        if (tid < s) red[tid] += red[tid + s];
        __syncthreads();
    }
    if (tid == 0) Sp[blockIdx.x] = red[0];
}

// out[j] = sum_t (E[t]/S) * f[t, j]
__global__ void weighted_sum(const float* __restrict__ E, const float* __restrict__ Sp,
                             const float* __restrict__ f, float* __restrict__ out) {
    float S = 0.f;
#pragma unroll
    for (int k = 0; k < 16; ++k) S += Sp[k];
    int jl = threadIdx.x & 63, tq = threadIdx.x >> 6;
    int j = blockIdx.x * 64 + jl;
    float acc = 0.f;
    int tbase = blockIdx.y * 512 + tq * 128;
    for (int i = 0; i < 128; ++i) {
        int t = tbase + i;
        acc = fmaf(E[t], f[(size_t)t * D_MODEL + j], acc);
    }
    __shared__ float sred[4][64];
    sred[tq][jl] = acc;
    __syncthreads();
    if (tq == 0)
        atomicAdd(&out[j], (sred[0][jl] + sred[1][jl] + sred[2][jl] + sred[3][jl]) / S);
}

// ---------------------------------------------------------------------------
// Host-side orchestration
// ---------------------------------------------------------------------------
extern "C" void kernel_launch(void* const* d_in, const int* in_sizes, int n_in,
                              void* d_out, int out_size, void* d_ws, size_t ws_size,
                              hipStream_t stream) {
    (void)in_sizes; (void)n_in; (void)out_size; (void)ws_size;
    const float* x = (const float*)d_in[0];
    const float* m_in_w[2]   = {(const float*)d_in[1],  (const float*)d_in[10]};
    const float* m_conv_w[2] = {(const float*)d_in[2],  (const float*)d_in[11]};
    const float* m_conv_b[2] = {(const float*)d_in[3],  (const float*)d_in[12]};
    const float* m_xproj[2]  = {(const float*)d_in[4],  (const float*)d_in[13]};
    const float* m_dt_w[2]   = {(const float*)d_in[5],  (const float*)d_in[14]};
    const float* m_dt_b[2]   = {(const float*)d_in[6],  (const float*)d_in[15]};
    const float* m_A_log[2]  = {(const float*)d_in[7],  (const float*)d_in[16]};
    const float* m_D[2]      = {(const float*)d_in[8],  (const float*)d_in[17]};
    const float* m_out_w[2]  = {(const float*)d_in[9],  (const float*)d_in[18]};
    const float* attn_w1 = (const float*)d_in[19];
    const float* attn_b1 = (const float*)d_in[20];
    const float* attn_w2 = (const float*)d_in[21];
    const float* attn_b2 = (const float*)d_in[22];

    const int L = L_SEQ;
    float* ws = (float*)d_ws;
    // Regions (floats); overlays noted.
    float* XIN   = ws;                                   // L*1024; AaugOut head
    float* AUXA  = XIN  + (size_t)L * 1024;              // 2,097,152 ; AaugOut tail
    float* Z     = AUXA + 2097152;                       // L*1024; OutP slab 0-1
    float* U     = Z    + (size_t)L * 1024;              // L*1024; OutP slab 2-3
    float* XDBL  = U    + (size_t)L * 1024;              // L*64
    float* FREG  = XDBL + (size_t)L * 64;                // 3,145,728: AaugIn / F2+HA+E+Sp
    float* W1i   = FREG + 3145728;                       // WaugIn1  1,572,864
    float* W1o   = W1i  + 1572864;                       // WaugOut1   786,432
    float* W2i   = W1o  + 786432;                        // WaugIn2  1,572,864
    float* W2o   = W2i  + 1572864;                       // WaugOut2   786,432
    float* P     = W2o  + 786432;                        // 2,097,152; partials overlay
    float* HLOC  = P    + (size_t)NCHUNK * D_INNER * D_STATE;

    bf16* AaugOut = (bf16*)XIN;    // [L,3072] bf16 spans XIN+AUXA
    bf16* AaugIn  = (bf16*)FREG;   // [L,1536] bf16
    bf16* WaugIn[2]  = {(bf16*)W1i, (bf16*)W2i};
    bf16* WaugOut[2] = {(bf16*)W1o, (bf16*)W2o};
    float* XDBLP = P;              // 8 x L*64 split-K partials (pre-scan)
    float* OutP  = Z;              // 4 x L*512 split-K partials (post-pass3; Z+U dead)
    float* F2    = FREG;           // mamba2 output [L,512] (AaugIn dead by then)
    float* HA    = FREG + 2097152; // attention hidden [L,128]
    float* HAP   = P;              // 4 x L*128 attn split-K partials (P dead post-mamba2)
    float* E     = HA + 524288;    // exp(logits) [L]
    float* Sp    = E + L;          // 16 partial sums

    // ---- all weight/x splits in one launch ----
    split_all_k<<<(2 * N_INW + 2 * N_OUTW + N_X) / 256, 256, 0, stream>>>(
        m_in_w[0], m_out_w[0], m_in_w[1], m_out_w[1], x,
        WaugIn[0], WaugOut[0], WaugIn[1], WaugOut[1], AaugIn);

    auto mamba = [&](int b, float* FoutY, bf16* FoutAug) {
        // in_proj: [XIN|Z] = AaugIn @ WaugIn^T   (M=L, N=2048, K'=1536)
        gemm_bf16<128, 64, 1><<<dim3(32, 32, 1), 256, 0, stream>>>(
            AaugIn, WaugIn[b], XIN, Z, 1024, 1024, L, 2048, 1536);
        conv_silu_k<<<(L * D_INNER + 255) / 256, 256, 0, stream>>>(XIN, m_conv_w[b], m_conv_b[b], U);
        // xdbl = U @ xproj^T  (split-K=8)
        sgemm<64, 64, 4, 4><<<dim3(1, L / 64, 8), 256, 0, stream>>>(
            U, D_INNER, m_xproj[b], D_INNER, XDBLP, 64, L, 64, D_INNER);
        reduce_aug_k<<<(L * 64 + 255) / 256, 256, 0, stream>>>(XDBLP, XDBL, nullptr, L * 64, 8);
        // chunked scan (dt GEMM fused inline); pass3 emits augmented bf16
        scan_pass1<<<dim3(NCHUNK, 4), 256, 0, stream>>>(
            U, XDBL, m_dt_w[b], m_dt_b[b], m_A_log[b], P, HLOC);
        scan_pass2<<<(D_INNER * D_STATE) / 256, 256, 0, stream>>>(P, HLOC);
        scan_pass3<<<dim3(NCHUNK, 4), 256, 0, stream>>>(
            U, XDBL, m_dt_w[b], m_dt_b[b], m_A_log[b], m_D[b], Z, HLOC, AaugOut);
        // out_proj: split-K=4  (M=L, N=512, K'=3072), partials on dead Z+U
        gemm_bf16<64, 128, 4><<<dim3(4, 64, 4), 256, 0, stream>>>(
            AaugOut, WaugOut[b], OutP, nullptr, 512, 512, L, 512, 3072);
        reduce_aug_k<<<(L * 512 + 255) / 256, 256, 0, stream>>>(OutP, FoutY, FoutAug, L * 512, 4);
    };

    mamba(0, nullptr, AaugIn);   // mamba1 -> next block's augmented input
    mamba(1, F2, nullptr);       // mamba2 -> F2 fp32

    // attention: HA = x @ w1^T  (split-K=4)
    sgemm<64, 64, 4, 4><<<dim3(ATT_D / 64, L / 64, 4), 256, 0, stream>>>(
        x, D_MODEL, attn_w1, D_MODEL, HAP, ATT_D, L, ATT_D, D_MODEL);
    reduce_aug_k<<<(L * ATT_D + 255) / 256, 256, 0, stream>>>(HAP, HA, nullptr, L * ATT_D, 4);
    attn_logits_exp<<<L / 256, 256, 0, stream>>>(HA, attn_b1, attn_w2, attn_b2, E, Sp);
    hipMemsetAsync(d_out, 0, D_MODEL * sizeof(float), stream);
    weighted_sum<<<dim3(D_MODEL / 64, 8), 256, 0, stream>>>(E, Sp, F2, (float*)d_out);
}

// Round 7
// 548.676 us; speedup vs baseline: 2.0191x; 1.0340x over previous
//
#include <hip/hip_runtime.h>
#include <cstddef>
#include <cstdint>

// ---------------------------------------------------------------------------
// Problem constants
// ---------------------------------------------------------------------------
#define L_SEQ   4096
#define D_MODEL 512
#define D_INNER 1024
#define D_STATE 16
#define DT_RANK 32
#define ATT_D   128
#define NCHUNK  128    // 128 chunks x 32 steps = 4096
#define CLEN    32

typedef __bf16 bf16;
typedef __bf16 bf16x8 __attribute__((ext_vector_type(8)));
typedef float  f32x4  __attribute__((ext_vector_type(4)));

__device__ __forceinline__ void load_lds16(const void* g, void* l) {
    __builtin_amdgcn_global_load_lds(
        (const __attribute__((address_space(1))) uint32_t*)g,
        (__attribute__((address_space(3))) uint32_t*)l, 16, 0, 0);
}

// ---------------------------------------------------------------------------
// bf16 MFMA GEMM: 128x128 block, 2x2 waves (64x64 wave tile), 4x4 register
// blocking of 16x16x32 MFMA -> 16 MFMAs per 8 ds_read_b128 per iter
// (32 FLOP / LDS byte).  Double-buffered, XOR-swizzled LDS (0 conflicts).
// C[M,N] = A[M,K] * B[N,K]^T (fp32 out).  Optional split-K (NSPLIT slabs of
// M*ldc at the C base) and dual output planes (col < csplit -> C0 else C1).
// ---------------------------------------------------------------------------
template <int NSPLIT>
__global__ void __launch_bounds__(256) gemm_bf16(const bf16* __restrict__ A,
                                                 const bf16* __restrict__ B,
                                                 float* __restrict__ C0,
                                                 float* __restrict__ C1,
                                                 int csplit, int ldc,
                                                 int M, int N, int K) {
    constexpr int BM = 128, BN = 128, BK = 32;
    constexpr int TM = 4, TN = 4;
    __shared__ bf16 As[2][BM][BK];
    __shared__ bf16 Bs[2][BN][BK];
    const int tid  = threadIdx.x;
    const int lane = tid & 63;
    const int wid  = tid >> 6;
    const int wm   = wid >> 1;
    const int wn   = wid & 1;
    const int m_l  = lane & 15;
    const int quad = lane >> 4;
    const int row0 = blockIdx.y * BM;
    const int col0 = blockIdx.x * BN;

    const int kper = K / NSPLIT;
    const int kbeg = blockIdx.z * kper;
    const int iters = kper / BK;

    f32x4 acc[TM][TN] = {};

    // stage: 512 16B slots per operand tile; slot = row*4 + pos,
    // global chunk at pos = pos ^ ((row>>1)&3)  (swizzle, 0-conflict reads)
    auto stage = [&](int k0, int buf) {
#pragma unroll
        for (int r = 0; r < 2; ++r) {
            int sl  = tid + r * 256;
            int row = sl >> 2;
            int ch  = (sl & 3) ^ ((row >> 1) & 3);
            load_lds16(A + (size_t)(row0 + row) * K + k0 + ch * 8,
                       (char*)&As[buf][0][0] + sl * 16);
        }
#pragma unroll
        for (int r = 0; r < 2; ++r) {
            int sl  = tid + r * 256;
            int row = sl >> 2;
            int ch  = (sl & 3) ^ ((row >> 1) & 3);
            load_lds16(B + (size_t)(col0 + row) * K + k0 + ch * 8,
                       (char*)&Bs[buf][0][0] + sl * 16);
        }
    };

    stage(kbeg, 0);
    for (int it = 0; it < iters; ++it) {
        int cur = it & 1;
        __syncthreads();                 // drains prefetch for 'cur'
        if (it + 1 < iters) stage(kbeg + (it + 1) * BK, cur ^ 1);

        bf16x8 af[TM], bfr[TN];
#pragma unroll
        for (int i = 0; i < TM; ++i) {
            int r = wm * 64 + i * 16 + m_l;
            af[i] = *(const bf16x8*)&As[cur][r][(quad ^ ((r >> 1) & 3)) * 8];
        }
#pragma unroll
        for (int j = 0; j < TN; ++j) {
            int r = wn * 64 + j * 16 + m_l;
            bfr[j] = *(const bf16x8*)&Bs[cur][r][(quad ^ ((r >> 1) & 3)) * 8];
        }
#pragma unroll
        for (int i = 0; i < TM; ++i)
#pragma unroll
            for (int j = 0; j < TN; ++j)
                acc[i][j] = __builtin_amdgcn_mfma_f32_16x16x32_bf16(
                                af[i], bfr[j], acc[i][j], 0, 0, 0);
    }
    // C/D layout: col = lane&15, row = quad*4 + reg
#pragma unroll
    for (int i = 0; i < TM; ++i)
#pragma unroll
        for (int j = 0; j < TN; ++j) {
            int rr = row0 + wm * 64 + i * 16 + quad * 4;
            int cc = col0 + wn * 64 + j * 16 + m_l;
            float* base; int c2;
            if (cc < csplit) { base = C0; c2 = cc; }
            else             { base = C1; c2 = cc - csplit; }
            base += (size_t)blockIdx.z * (size_t)M * ldc;
#pragma unroll
            for (int g = 0; g < 4; ++g)
                base[(size_t)(rr + g) * ldc + c2] = acc[i][j][g];
        }
}

// ---------------------------------------------------------------------------
// One-launch weight/activation splitting into augmented bf16.
// wt rows: [hi|hi|lo]  act rows: [hi|lo|hi]
// ---------------------------------------------------------------------------
#define N_INW  (2048 * 512)
#define N_OUTW (512 * 1024)
#define N_X    (4096 * 512)

__global__ void split_all_k(const float* __restrict__ in_w0, const float* __restrict__ out_w0,
                            const float* __restrict__ in_w1, const float* __restrict__ out_w1,
                            const float* __restrict__ x,
                            bf16* __restrict__ Win0, bf16* __restrict__ Wout0,
                            bf16* __restrict__ Win1, bf16* __restrict__ Wout1,
                            bf16* __restrict__ Ax) {
    int i = blockIdx.x * 256 + threadIdx.x;
    const float* src; bf16* dst; int K; int act = 0;
    if (i < N_INW)                  { src = in_w0;  dst = Win0;  K = 512; }
    else if ((i -= N_INW) < N_OUTW) { src = out_w0; dst = Wout0; K = 1024; }
    else if ((i -= N_OUTW) < N_INW) { src = in_w1;  dst = Win1;  K = 512; }
    else if ((i -= N_INW) < N_OUTW) { src = out_w1; dst = Wout1; K = 1024; }
    else if ((i -= N_OUTW) < N_X)   { src = x;      dst = Ax;    K = 512; act = 1; }
    else return;
    int row = i / K, col = i - row * K;
    float v = src[i];
    bf16 h = (bf16)v;
    bf16 l = (bf16)(v - (float)h);
    bf16* yr = dst + (size_t)row * 3 * K;
    if (act) { yr[col] = h; yr[K + col] = l; yr[2 * K + col] = h; }
    else     { yr[col] = h; yr[K + col] = h; yr[2 * K + col] = l; }
}

// ---------------------------------------------------------------------------
// fp32 SGEMM (small GEMMs), split-K via gridDim.z.
// ---------------------------------------------------------------------------
template <int BM, int BN, int TM, int TN>
__global__ void __launch_bounds__(256) sgemm(const float* __restrict__ A, int lda,
                                             const float* __restrict__ B, int ldb,
                                             float* __restrict__ C, int ldc,
                                             int M, int N, int K) {
    constexpr int BK = 16;
    __shared__ float As[BK][BM + 4];
    __shared__ float Bs[BK][BN + 4];
    const int tid = threadIdx.x;
    const int tx = tid & 15;
    const int ty = tid >> 4;
    const int row0 = blockIdx.y * BM;
    const int col0 = blockIdx.x * BN;
    const int nz = gridDim.z;
    const int kper = K / nz;
    const int kbeg = blockIdx.z * kper, kend = kbeg + kper;
    float* Cz = C + (size_t)blockIdx.z * M * ldc;

    float acc[TM][TN] = {};

    for (int k0 = kbeg; k0 < kend; k0 += BK) {
#pragma unroll
        for (int i = 0; i < (BM * BK) / (256 * 4); ++i) {
            int lin = tid + i * 256;
            int m = lin >> 2;
            int kk = (lin & 3) << 2;
            float4 v = *(const float4*)(A + (size_t)(row0 + m) * lda + k0 + kk);
            As[kk + 0][m] = v.x; As[kk + 1][m] = v.y;
            As[kk + 2][m] = v.z; As[kk + 3][m] = v.w;
        }
#pragma unroll
        for (int i = 0; i < (BN * BK) / (256 * 4); ++i) {
            int lin = tid + i * 256;
            int m = lin >> 2;
            int kk = (lin & 3) << 2;
            float4 v = *(const float4*)(B + (size_t)(col0 + m) * ldb + k0 + kk);
            Bs[kk + 0][m] = v.x; Bs[kk + 1][m] = v.y;
            Bs[kk + 2][m] = v.z; Bs[kk + 3][m] = v.w;
        }
        __syncthreads();
#pragma unroll
        for (int k = 0; k < BK; ++k) {
            float a[TM], b[TN];
#pragma unroll
            for (int i = 0; i < TM; ++i) a[i] = As[k][ty * TM + i];
#pragma unroll
            for (int j = 0; j < TN; ++j) b[j] = Bs[k][tx * TN + j];
#pragma unroll
            for (int i = 0; i < TM; ++i)
#pragma unroll
                for (int j = 0; j < TN; ++j)
                    acc[i][j] = fmaf(a[i], b[j], acc[i][j]);
        }
        __syncthreads();
    }
#pragma unroll
    for (int i = 0; i < TM; ++i) {
        size_t r = (size_t)(row0 + ty * TM + i);
#pragma unroll
        for (int j = 0; j < TN; ++j)
            Cz[r * ldc + col0 + tx * TN + j] = acc[i][j];
    }
}

// Sum nslab split-K slabs; optional fp32 Y and/or augmented bf16 (width 512).
__global__ void reduce_aug_k(const float* __restrict__ Pp, float* __restrict__ Y,
                             bf16* __restrict__ Aaug, int n, int nslab) {
    int i = blockIdx.x * 256 + threadIdx.x;
    if (i >= n) return;
    float v = 0.f;
    for (int k = 0; k < nslab; ++k) v += Pp[(size_t)k * n + i];
    if (Y) Y[i] = v;
    if (Aaug) {
        int row = i >> 9, col = i & 511;
        bf16 h = (bf16)v;
        bf16 l = (bf16)(v - (float)h);
        bf16* r = Aaug + (size_t)row * 1536;
        r[col] = h; r[512 + col] = l; r[1024 + col] = h;
    }
}

// ---------------------------------------------------------------------------
// Depthwise causal conv (k=4) + bias + silu.  XIN plane [L, 1024].
// ---------------------------------------------------------------------------
__global__ void conv_silu_k(const float* __restrict__ XIN, const float* __restrict__ cw,
                            const float* __restrict__ cb, float* __restrict__ U) {
    int i = blockIdx.x * 256 + threadIdx.x;
    if (i >= L_SEQ * D_INNER) return;
    int t = i >> 10;
    int d = i & (D_INNER - 1);
    float acc = cb[d];
#pragma unroll
    for (int k = 0; k < 4; ++k) {
        int tt = t - 3 + k;
        if (tt >= 0) acc = fmaf(cw[d * 4 + k], XIN[(size_t)tt * D_INNER + d], acc);
    }
    U[i] = acc / (1.f + __expf(-acc));
}

// ---------------------------------------------------------------------------
// Chunked selective scan, channel-per-lane; dt GEMM (K=32) + bias + softplus
// fused inline.  pass3 writes the augmented bf16 A-operand for out_proj.
// ---------------------------------------------------------------------------
__device__ __forceinline__ float softplus_f(float v) {
    return (v > 20.f) ? v : log1pf(__expf(v));
}

__global__ void __launch_bounds__(256) scan_pass1(
        const float* __restrict__ U, const float* __restrict__ XDBL,
        const float* __restrict__ dt_w, const float* __restrict__ dtb,
        const float* __restrict__ A_log, float* __restrict__ P,
        float* __restrict__ HLOC) {
    const int d = blockIdx.y * 256 + threadIdx.x;
    const int c = blockIdx.x;
    float Ac[16];
#pragma unroll
    for (int q = 0; q < 4; ++q) {
        float4 v = *(const float4*)(A_log + (size_t)d * 16 + q * 4);
        Ac[q*4+0] = -__expf(v.x); Ac[q*4+1] = -__expf(v.y);
        Ac[q*4+2] = -__expf(v.z); Ac[q*4+3] = -__expf(v.w);
    }
    float wdt[32];
#pragma unroll
    for (int q = 0; q < 8; ++q) {
        float4 v = *(const float4*)(dt_w + (size_t)d * 32 + q * 4);
        wdt[q*4+0] = v.x; wdt[q*4+1] = v.y; wdt[q*4+2] = v.z; wdt[q*4+3] = v.w;
    }
    const float bias = dtb[d];
    float h[16] = {};
    float Pp[16];
#pragma unroll
    for (int s = 0; s < 16; ++s) Pp[s] = 1.f;

    const int t0 = c * CLEN;
    for (int i = 0; i < CLEN; ++i) {
        int t = t0 + i;
        const float4* xr = (const float4*)(XDBL + (size_t)t * 64);
        float dot = bias;
#pragma unroll
        for (int q = 0; q < 8; ++q) {
            float4 v = xr[q];
            dot = fmaf(v.x, wdt[q*4+0], dot); dot = fmaf(v.y, wdt[q*4+1], dot);
            dot = fmaf(v.z, wdt[q*4+2], dot); dot = fmaf(v.w, wdt[q*4+3], dot);
        }
        float dtv = softplus_f(dot);
        float uu  = U[(size_t)t * D_INNER + d];
        float duu = dtv * uu;
        float4 B0 = xr[8], B1 = xr[9], B2 = xr[10], B3 = xr[11];
        float Bv[16] = {B0.x,B0.y,B0.z,B0.w, B1.x,B1.y,B1.z,B1.w,
                        B2.x,B2.y,B2.z,B2.w, B3.x,B3.y,B3.z,B3.w};
#pragma unroll
        for (int s = 0; s < 16; ++s) {
            float dA = __expf(dtv * Ac[s]);
            h[s] = fmaf(dA, h[s], duu * Bv[s]);
            Pp[s] *= dA;
        }
    }
#pragma unroll
    for (int s = 0; s < 16; ++s) {
        size_t idx = (size_t)c * (D_INNER * D_STATE) + s * D_INNER + d;
        P[idx] = Pp[s];
        HLOC[idx] = h[s];
    }
}

__global__ void scan_pass2(const float* __restrict__ P, float* HLOC) {
    int g = blockIdx.x * 256 + threadIdx.x;
    const int STRIDE = D_INNER * D_STATE;
    float h = 0.f;
    for (int c = 0; c < NCHUNK; ++c) {
        float tmp = fmaf(P[(size_t)c * STRIDE + g], h, HLOC[(size_t)c * STRIDE + g]);
        HLOC[(size_t)c * STRIDE + g] = h;     // now holds incoming state
        h = tmp;
    }
}

__global__ void __launch_bounds__(256) scan_pass3(
        const float* __restrict__ U, const float* __restrict__ XDBL,
        const float* __restrict__ dt_w, const float* __restrict__ dtb,
        const float* __restrict__ A_log, const float* __restrict__ Dp,
        const float* __restrict__ Z, const float* __restrict__ HIN,
        bf16* __restrict__ Aaug) {
    const int d = blockIdx.y * 256 + threadIdx.x;
    const int c = blockIdx.x;
    float Ac[16];
#pragma unroll
    for (int q = 0; q < 4; ++q) {
        float4 v = *(const float4*)(A_log + (size_t)d * 16 + q * 4);
        Ac[q*4+0] = -__expf(v.x); Ac[q*4+1] = -__expf(v.y);
        Ac[q*4+2] = -__expf(v.z); Ac[q*4+3] = -__expf(v.w);
    }
    float wdt[32];
#pragma unroll
    for (int q = 0; q < 8; ++q) {
        float4 v = *(const float4*)(dt_w + (size_t)d * 32 + q * 4);
        wdt[q*4+0] = v.x; wdt[q*4+1] = v.y; wdt[q*4+2] = v.z; wdt[q*4+3] = v.w;
    }
    const float bias = dtb[d];
    const float Dv = Dp[d];
    float h[16];
#pragma unroll
    for (int s = 0; s < 16; ++s)
        h[s] = HIN[(size_t)c * (D_INNER * D_STATE) + s * D_INNER + d];

    const int t0 = c * CLEN;
    for (int i = 0; i < CLEN; ++i) {
        int t = t0 + i;
        const float4* xr = (const float4*)(XDBL + (size_t)t * 64);
        float dot = bias;
#pragma unroll
        for (int q = 0; q < 8; ++q) {
            float4 v = xr[q];
            dot = fmaf(v.x, wdt[q*4+0], dot); dot = fmaf(v.y, wdt[q*4+1], dot);
            dot = fmaf(v.z, wdt[q*4+2], dot); dot = fmaf(v.w, wdt[q*4+3], dot);
        }
        float dtv = softplus_f(dot);
        float uu  = U[(size_t)t * D_INNER + d];
        float duu = dtv * uu;
        float4 B0 = xr[8],  B1 = xr[9],  B2 = xr[10], B3 = xr[11];
        float4 C0 = xr[12], C1 = xr[13], C2 = xr[14], C3 = xr[15];
        float Bv[16] = {B0.x,B0.y,B0.z,B0.w, B1.x,B1.y,B1.z,B1.w,
                        B2.x,B2.y,B2.z,B2.w, B3.x,B3.y,B3.z,B3.w};
        float Cv[16] = {C0.x,C0.y,C0.z,C0.w, C1.x,C1.y,C1.z,C1.w,
                        C2.x,C2.y,C2.z,C2.w, C3.x,C3.y,C3.z,C3.w};
        float p = 0.f;
#pragma unroll
        for (int s = 0; s < 16; ++s) {
            float dA = __expf(dtv * Ac[s]);
            h[s] = fmaf(dA, h[s], duu * Bv[s]);
            p = fmaf(h[s], Cv[s], p);
        }
        float y = fmaf(uu, Dv, p);
        float z = Z[(size_t)t * D_INNER + d];
        float sz = z / (1.f + __expf(-z));
        float g = y * sz;
        bf16 hi = (bf16)g;
        bf16 lo = (bf16)(g - (float)hi);
        bf16* row = Aaug + (size_t)t * 3072;
        row[d] = hi; row[1024 + d] = lo; row[2048 + d] = hi;
    }
}

// ---------------------------------------------------------------------------
// Attention head.  |logit| <= sum|w2| (+|b2|) ~ 5 (tanh-bounded) -> safe to
// skip the max-subtraction pass.
// ---------------------------------------------------------------------------
__global__ void attn_logits_exp(const float* __restrict__ ha, const float* __restrict__ b1,
                                const float* __restrict__ w2, const float* __restrict__ b2,
                                float* __restrict__ E, float* __restrict__ Sp) {
    int t = blockIdx.x * 256 + threadIdx.x;
    float acc = b2[0];
#pragma unroll 4
    for (int j = 0; j < ATT_D; ++j)
        acc = fmaf(tanhf(ha[(size_t)t * ATT_D + j] + b1[j]), w2[j], acc);
    float e = __expf(acc);
    E[t] = e;
    __shared__ float red[256];
    int tid = threadIdx.x;
    red[tid] = e;
    __syncthreads();
    for (int s = 128; s > 0; s >>= 1) {
        if (tid < s) red[tid] += red[tid + s];
        __syncthreads();
    }
    if (tid == 0) Sp[blockIdx.x] = red[0];
}

// out[j] = sum_t (E[t]/S) * f[t, j]
__global__ void weighted_sum(const float* __restrict__ E, const float* __restrict__ Sp,
                             const float* __restrict__ f, float* __restrict__ out) {
    float S = 0.f;
#pragma unroll
    for (int k = 0; k < 16; ++k) S += Sp[k];
    int jl = threadIdx.x & 63, tq = threadIdx.x >> 6;
    int j = blockIdx.x * 64 + jl;
    float acc = 0.f;
    int tbase = blockIdx.y * 512 + tq * 128;
    for (int i = 0; i < 128; ++i) {
        int t = tbase + i;
        acc = fmaf(E[t], f[(size_t)t * D_MODEL + j], acc);
    }
    __shared__ float sred[4][64];
    sred[tq][jl] = acc;
    __syncthreads();
    if (tq == 0)
        atomicAdd(&out[j], (sred[0][jl] + sred[1][jl] + sred[2][jl] + sred[3][jl]) / S);
}

// ---------------------------------------------------------------------------
// Host-side orchestration
// ---------------------------------------------------------------------------
extern "C" void kernel_launch(void* const* d_in, const int* in_sizes, int n_in,
                              void* d_out, int out_size, void* d_ws, size_t ws_size,
                              hipStream_t stream) {
    (void)in_sizes; (void)n_in; (void)out_size; (void)ws_size;
    const float* x = (const float*)d_in[0];
    const float* m_in_w[2]   = {(const float*)d_in[1],  (const float*)d_in[10]};
    const float* m_conv_w[2] = {(const float*)d_in[2],  (const float*)d_in[11]};
    const float* m_conv_b[2] = {(const float*)d_in[3],  (const float*)d_in[12]};
    const float* m_xproj[2]  = {(const float*)d_in[4],  (const float*)d_in[13]};
    const float* m_dt_w[2]   = {(const float*)d_in[5],  (const float*)d_in[14]};
    const float* m_dt_b[2]   = {(const float*)d_in[6],  (const float*)d_in[15]};
    const float* m_A_log[2]  = {(const float*)d_in[7],  (const float*)d_in[16]};
    const float* m_D[2]      = {(const float*)d_in[8],  (const float*)d_in[17]};
    const float* m_out_w[2]  = {(const float*)d_in[9],  (const float*)d_in[18]};
    const float* attn_w1 = (const float*)d_in[19];
    const float* attn_b1 = (const float*)d_in[20];
    const float* attn_w2 = (const float*)d_in[21];
    const float* attn_b2 = (const float*)d_in[22];

    const int L = L_SEQ;
    float* ws = (float*)d_ws;
    // Regions (floats); overlays noted.
    float* XIN   = ws;                                   // L*1024; AaugOut head
    float* AUXA  = XIN  + (size_t)L * 1024;              // 2,097,152 ; AaugOut tail
    float* Z     = AUXA + 2097152;                       // L*1024; OutP slab 0-1
    float* U     = Z    + (size_t)L * 1024;              // L*1024; OutP slab 2-3
    float* XDBL  = U    + (size_t)L * 1024;              // L*64
    float* FREG  = XDBL + (size_t)L * 64;                // 3,145,728: AaugIn / F2+HA+E+Sp
    float* W1i   = FREG + 3145728;                       // WaugIn1  1,572,864
    float* W1o   = W1i  + 1572864;                       // WaugOut1   786,432
    float* W2i   = W1o  + 786432;                        // WaugIn2  1,572,864
    float* W2o   = W2i  + 1572864;                       // WaugOut2   786,432
    float* P     = W2o  + 786432;                        // 2,097,152; partials overlay
    float* HLOC  = P    + (size_t)NCHUNK * D_INNER * D_STATE;

    bf16* AaugOut = (bf16*)XIN;    // [L,3072] bf16 spans XIN+AUXA
    bf16* AaugIn  = (bf16*)FREG;   // [L,1536] bf16
    bf16* WaugIn[2]  = {(bf16*)W1i, (bf16*)W2i};
    bf16* WaugOut[2] = {(bf16*)W1o, (bf16*)W2o};
    float* XDBLP = P;              // 8 x L*64 split-K partials (pre-scan)
    float* OutP  = Z;              // 4 x L*512 split-K partials (post-pass3; Z+U dead)
    float* F2    = FREG;           // mamba2 output [L,512] (AaugIn dead by then)
    float* HA    = FREG + 2097152; // attention hidden [L,128]
    float* HAP   = P;              // 4 x L*128 attn split-K partials (P dead post-mamba2)
    float* E     = HA + 524288;    // exp(logits) [L]
    float* Sp    = E + L;          // 16 partial sums

    // ---- all weight/x splits in one launch ----
    split_all_k<<<(2 * N_INW + 2 * N_OUTW + N_X) / 256, 256, 0, stream>>>(
        m_in_w[0], m_out_w[0], m_in_w[1], m_out_w[1], x,
        WaugIn[0], WaugOut[0], WaugIn[1], WaugOut[1], AaugIn);

    auto mamba = [&](int b, float* FoutY, bf16* FoutAug) {
        // in_proj: [XIN|Z] = AaugIn @ WaugIn^T   (M=L, N=2048, K'=1536)
        gemm_bf16<1><<<dim3(16, 32, 1), 256, 0, stream>>>(
            AaugIn, WaugIn[b], XIN, Z, 1024, 1024, L, 2048, 1536);
        conv_silu_k<<<(L * D_INNER + 255) / 256, 256, 0, stream>>>(XIN, m_conv_w[b], m_conv_b[b], U);
        // xdbl = U @ xproj^T  (split-K=8)
        sgemm<64, 64, 4, 4><<<dim3(1, L / 64, 8), 256, 0, stream>>>(
            U, D_INNER, m_xproj[b], D_INNER, XDBLP, 64, L, 64, D_INNER);
        reduce_aug_k<<<(L * 64 + 255) / 256, 256, 0, stream>>>(XDBLP, XDBL, nullptr, L * 64, 8);
        // chunked scan (dt GEMM fused inline); pass3 emits augmented bf16
        scan_pass1<<<dim3(NCHUNK, 4), 256, 0, stream>>>(
            U, XDBL, m_dt_w[b], m_dt_b[b], m_A_log[b], P, HLOC);
        scan_pass2<<<(D_INNER * D_STATE) / 256, 256, 0, stream>>>(P, HLOC);
        scan_pass3<<<dim3(NCHUNK, 4), 256, 0, stream>>>(
            U, XDBL, m_dt_w[b], m_dt_b[b], m_A_log[b], m_D[b], Z, HLOC, AaugOut);
        // out_proj: split-K=4  (M=L, N=512, K'=3072), partials on dead Z+U
        gemm_bf16<4><<<dim3(4, 32, 4), 256, 0, stream>>>(
            AaugOut, WaugOut[b], OutP, nullptr, 512, 512, L, 512, 3072);
        reduce_aug_k<<<(L * 512 + 255) / 256, 256, 0, stream>>>(OutP, FoutY, FoutAug, L * 512, 4);
    };

    mamba(0, nullptr, AaugIn);   // mamba1 -> next block's augmented input
    mamba(1, F2, nullptr);       // mamba2 -> F2 fp32

    // attention: HA = x @ w1^T  (split-K=4)
    sgemm<64, 64, 4, 4><<<dim3(ATT_D / 64, L / 64, 4), 256, 0, stream>>>(
        x, D_MODEL, attn_w1, D_MODEL, HAP, ATT_D, L, ATT_D, D_MODEL);
    reduce_aug_k<<<(L * ATT_D + 255) / 256, 256, 0, stream>>>(HAP, HA, nullptr, L * ATT_D, 4);
    attn_logits_exp<<<L / 256, 256, 0, stream>>>(HA, attn_b1, attn_w2, attn_b2, E, Sp);
    hipMemsetAsync(d_out, 0, D_MODEL * sizeof(float), stream);
    weighted_sum<<<dim3(D_MODEL / 64, 8), 256, 0, stream>>>(E, Sp, F2, (float*)d_out);
}